// Round 8
// baseline (1052.211 us; speedup 1.0000x reference)
//
#include <hip/hip_runtime.h>
#include <hip/hip_bf16.h>
#include <cstdint>

#define NN   100000
#define TT   4
#define EE   250000
#define LL   2
#define NCH  49            // ceil(NN/2048)
#define N64  ((size_t)NN * 64)

typedef unsigned short ushort_t;
typedef __attribute__((ext_vector_type(8))) short bf16x8;
typedef __attribute__((ext_vector_type(16))) float floatx16;
typedef __attribute__((ext_vector_type(4))) float floatx4;

static __device__ __forceinline__ float gelu_exact(float v) {
    return 0.5f * v * (1.0f + erff(v * 0.7071067811865476f));
}
static __device__ __forceinline__ float wave_sum64(float v) {
    #pragma unroll
    for (int m = 32; m; m >>= 1) v += __shfl_xor(v, m, 64);
    return v;
}
// fp32 -> bf16 round-to-nearest-even (finite inputs only)
static __device__ __forceinline__ ushort_t f2bf(float f) {
    unsigned u = __float_as_uint(f);
    u += 0x7FFFu + ((u >> 16) & 1u);
    return (ushort_t)(u >> 16);
}
static __device__ __forceinline__ float bf2f(ushort_t h) {
    return __uint_as_float((unsigned)h << 16);
}
// async global->LDS 16B (per-lane global addr; LDS dest = wave base + lane*16)
static __device__ __forceinline__ void gl_lds16(const ushort_t* g, ushort_t* l) {
    __builtin_amdgcn_global_load_lds(
        (const __attribute__((address_space(1))) void*)g,
        (__attribute__((address_space(3))) void*)l, 16, 0, 0);
}

// ---------------------------------------------------------------------------
// Prep: GEMM B-operands as TRANSPOSED split-bf16 planes [n][k]:
//  wcollT[l][col][d]  (K=64)   col = t*8+side*4+h, from W·a dot products
//  linwT[c][k]        (K=256)  from lin_w[k][c]
//  bprojT[l][c][kidx] (K=1024) kidx = t*256 + d*4 + h  (d-major, h-minor to
//                     match the fused kernel's z layout; verified round 6)
//  bsum[l][c] = sum_t conv_bias
// ---------------------------------------------------------------------------
__global__ __launch_bounds__(256) void k_prep(
    const float* __restrict__ Wsrc, const float* __restrict__ Wdst,
    const float* __restrict__ asrc, const float* __restrict__ adst,
    const float* __restrict__ cb, const float* __restrict__ lin_w,
    ushort_t* __restrict__ wcTh, ushort_t* __restrict__ wcTl,
    ushort_t* __restrict__ lwTh, ushort_t* __restrict__ lwTl,
    ushort_t* __restrict__ bpTh, ushort_t* __restrict__ bpTl,
    float* __restrict__ bsum)
{
    int id = blockIdx.x * 256 + threadIdx.x;   // grid = 131072 exactly
    {   // bprojT: id = ((((l*4+t)*4+h)*64 + c)*64 + d)
        int d = id & 63;
        int c = (id >> 6) & 63;
        int h = (id >> 12) & 3;
        int t = (id >> 14) & 3;
        int l = (id >> 16) & 1;
        float v = 0.25f * Wsrc[(((l * 4 + t) * 64 + d) * 256) + h * 64 + c];
        int dst = (l * 64 + c) * 1024 + (t * 256 + d * 4 + h);
        ushort_t hh = f2bf(v);
        bpTh[dst] = hh;
        bpTl[dst] = f2bf(v - bf2f(hh));
    }
    if (id < LL * 64 * 64) {   // wcollT
        int d   = id & 63;
        int col = (id >> 6) & 63;
        int l   = (id >> 12) & 1;
        int t = col >> 3, side = (col >> 2) & 1, h = col & 3;
        const float* W = side ? Wdst : Wsrc;
        const float* a = side ? adst : asrc;
        int wb = ((l * 4 + t) * 64 + d) * 256 + h * 64;
        int ab = ((l * 4 + t) * 4 + h) * 64;
        float s = 0.f;
        #pragma unroll 8
        for (int c2 = 0; c2 < 64; ++c2) s = fmaf(W[wb + c2], a[ab + c2], s);
        int dst = (l * 64 + col) * 64 + d;
        ushort_t hh = f2bf(s);
        wcTh[dst] = hh;
        wcTl[dst] = f2bf(s - bf2f(hh));
    }
    if (id < 64 * 256) {       // linwT: c = id>>8, k = id&255
        int k = id & 255, c = id >> 8;
        float v = lin_w[k * 64 + c];
        ushort_t hh = f2bf(v);
        lwTh[c * 256 + k] = hh;
        lwTl[c * 256 + k] = f2bf(v - bf2f(hh));
    }
    if (id < LL * 64) {        // bias_sum
        int l = id >> 6, c = id & 63;
        float s = 0.f;
        for (int t = 0; t < TT; ++t) s += cb[(l * 4 + t) * 64 + c];
        bsum[id] = s;
    }
}

// ---------------------------------------------------------------------------
// CSR build over REAL edges only (self-loops handled inline in k_fused).
// ---------------------------------------------------------------------------
__global__ void k_hist(const int* __restrict__ ei, int* __restrict__ cursor) {
    int id = blockIdx.x * 256 + threadIdx.x;
    if (id >= TT * EE) return;
    int t = id / EE, e = id - t * EE;
    int d = ei[(t * 2 + 1) * EE + e];
    atomicAdd(&cursor[t * NN + d], 1);
}

__global__ __launch_bounds__(256) void k_scan1(const int* __restrict__ deg,
                                               int* __restrict__ csum) {
    int b = blockIdx.x, t = b / NCH, cc = b - t * NCH;
    int tid = threadIdx.x;
    int base = cc * 2048 + tid * 8;
    int s = 0;
    #pragma unroll
    for (int i = 0; i < 8; ++i) {
        int idx = base + i;
        if (idx < NN) s += deg[t * NN + idx];       // real edges only
    }
    #pragma unroll
    for (int m = 32; m; m >>= 1) s += __shfl_xor(s, m, 64);
    __shared__ int ws4[4];
    int lane = tid & 63, wid = tid >> 6;
    if (lane == 0) ws4[wid] = s;
    __syncthreads();
    if (tid == 0) csum[b] = ws4[0] + ws4[1] + ws4[2] + ws4[3];
}

__global__ void k_scan2(const int* __restrict__ csum, int* __restrict__ cbase,
                        int* __restrict__ row_ptr) {
    int t = threadIdx.x;
    if (t >= TT) return;
    int base = 0;
    for (int c = 0; c < NCH; ++c) {
        cbase[t * NCH + c] = base;
        base += csum[t * NCH + c];
    }
    row_ptr[t * (NN + 1) + NN] = base;   // = EE
}

__global__ __launch_bounds__(256) void k_scan3(int* __restrict__ cursor,
                                               const int* __restrict__ cbase,
                                               int* __restrict__ row_ptr) {
    int b = blockIdx.x, t = b / NCH, cc = b - t * NCH;
    int tid = threadIdx.x, lane = tid & 63, wid = tid >> 6;
    int base = cc * 2048 + tid * 8;
    int vals[8], ts = 0;
    #pragma unroll
    for (int i = 0; i < 8; ++i) {
        int idx = base + i;
        int v = (idx < NN) ? cursor[t * NN + idx] : 0;   // no self slot
        vals[i] = v; ts += v;
    }
    int v = ts;
    #pragma unroll
    for (int off = 1; off < 64; off <<= 1) {
        int u = __shfl_up(v, off, 64);
        if (lane >= off) v += u;
    }
    __shared__ int wt[4];
    if (lane == 63) wt[wid] = v;
    __syncthreads();
    int wbase = 0;
    for (int w = 0; w < wid; ++w) wbase += wt[w];
    int run = cbase[t * NCH + cc] + wbase + (v - ts);
    #pragma unroll
    for (int i = 0; i < 8; ++i) {
        int idx = base + i;
        if (idx < NN) {
            row_ptr[t * (NN + 1) + idx] = run;
            cursor[t * NN + idx] = run;     // becomes scatter write-head
        }
        run += vals[i];
    }
}

__global__ void k_scatter(const int* __restrict__ ei, int* __restrict__ cursor,
                          int2* __restrict__ sd) {
    int id = blockIdx.x * 256 + threadIdx.x;
    if (id >= TT * EE) return;
    int t = id / EE, r = id - t * EE;
    int s = ei[t * 2 * EE + r];
    int d = ei[(t * 2 + 1) * EE + r];
    int pos = atomicAdd(&cursor[t * NN + d], 1);
    sd[(size_t)t * EE + pos] = make_int2(s, d);
}

// ---------------------------------------------------------------------------
// Split-bf16 MFMA GEMM, fp32 A (feature transform + s_all projection).
// C[N,64] = A[N,K] @ B[K,64]; A split into hi/lo during LDS staging.
// LDS: linear 64B rows, XOR chunk-swizzle applied on the source side.
// Fragment layouts (verified m74/m101/m120-lineage):
//   A[m][k]: m=lane&31, k=(lane>>5)*8+j    B[k][n]: n=lane&31, same k
//   C/D: col=lane&31 (+32*ct), row=(reg&3)+8*(reg>>2)+4*(lane>>5)
// ---------------------------------------------------------------------------
__global__ __launch_bounds__(256, 4) void k_gemm_f32a(
    const float* __restrict__ Af,
    const ushort_t* __restrict__ Bhi, const ushort_t* __restrict__ Blo,
    int K, int ldb, int nrows, float* __restrict__ Cout)
{
    constexpr int KC = 32;
    __shared__ ushort_t sAh[128 * 32], sAl[128 * 32];
    __shared__ ushort_t sBh[64 * 32],  sBl[64 * 32];
    const int tid = threadIdx.x;
    const int w = tid >> 6, ln = tid & 63;
    const int l31 = ln & 31, hl = ln >> 5;
    const int rowbase = blockIdx.x * 128;

    floatx16 accv[2];
    #pragma unroll
    for (int ct = 0; ct < 2; ++ct)
        #pragma unroll
        for (int r = 0; r < 16; ++r) accv[ct][r] = 0.f;

    for (int kc = 0; kc < K; kc += KC) {
        __syncthreads();
        // stage A: 128 rows x 32 k (4 chunks of 8), fp32 -> split-bf16
        #pragma unroll
        for (int i = 0; i < 2; ++i) {
            int f = tid + i * 256;           // 0..511
            int r = f >> 2, cg = f & 3;
            int row = rowbase + r;
            int sg = (r ^ (r >> 2)) & 3;
            int sw = r * 32 + ((cg ^ sg) << 3);
            if (row < nrows) {
                size_t ga = (size_t)row * K + kc + cg * 8;
                floatx4 v0 = *(const floatx4*)(Af + ga);
                floatx4 v1 = *(const floatx4*)(Af + ga + 4);
                float vf[8] = {v0.x, v0.y, v0.z, v0.w, v1.x, v1.y, v1.z, v1.w};
                unsigned hu[8], lu[8];
                #pragma unroll
                for (int q = 0; q < 8; ++q) {
                    ushort_t hh = f2bf(vf[q]);
                    hu[q] = hh;
                    lu[q] = f2bf(vf[q] - bf2f(hh));
                }
                uint4 H = make_uint4(hu[0] | (hu[1] << 16), hu[2] | (hu[3] << 16),
                                     hu[4] | (hu[5] << 16), hu[6] | (hu[7] << 16));
                uint4 L = make_uint4(lu[0] | (lu[1] << 16), lu[2] | (lu[3] << 16),
                                     lu[4] | (lu[5] << 16), lu[6] | (lu[7] << 16));
                *(uint4*)&sAh[sw] = H;
                *(uint4*)&sAl[sw] = L;
            } else {
                *(uint4*)&sAh[sw] = make_uint4(0, 0, 0, 0);
                *(uint4*)&sAl[sw] = make_uint4(0, 0, 0, 0);
            }
        }
        // stage B: 64 n-rows x 32 k, both planes, direct-to-LDS
        {
            int r = tid >> 2, cg = tid & 3;
            int sg = (r ^ (r >> 2)) & 3;
            int so = r * 32 + (cg << 3);
            size_t gb = (size_t)r * ldb + kc + ((cg ^ sg) << 3);
            gl_lds16(Bhi + gb, &sBh[so]);
            gl_lds16(Blo + gb, &sBl[so]);
        }
        __syncthreads();
        const int arow = (w << 5) + l31;
        const int sga = (arow ^ (arow >> 2)) & 3;
        const int sgb = (l31 ^ (l31 >> 2)) & 3;
        #pragma unroll
        for (int s = 0; s < 2; ++s) {
            const int c0 = (s << 1) | hl;
            const int ka = (c0 ^ sga) << 3;
            const int kb = (c0 ^ sgb) << 3;
            bf16x8 ah  = *(const bf16x8*)&sAh[arow * 32 + ka];
            bf16x8 al  = *(const bf16x8*)&sAl[arow * 32 + ka];
            bf16x8 bh0 = *(const bf16x8*)&sBh[l31 * 32 + kb];
            bf16x8 bl0 = *(const bf16x8*)&sBl[l31 * 32 + kb];
            bf16x8 bh1 = *(const bf16x8*)&sBh[(32 + l31) * 32 + kb];
            bf16x8 bl1 = *(const bf16x8*)&sBl[(32 + l31) * 32 + kb];
            accv[0] = __builtin_amdgcn_mfma_f32_32x32x16_bf16(ah, bh0, accv[0], 0, 0, 0);
            accv[1] = __builtin_amdgcn_mfma_f32_32x32x16_bf16(ah, bh1, accv[1], 0, 0, 0);
            accv[0] = __builtin_amdgcn_mfma_f32_32x32x16_bf16(al, bh0, accv[0], 0, 0, 0);
            accv[1] = __builtin_amdgcn_mfma_f32_32x32x16_bf16(al, bh1, accv[1], 0, 0, 0);
            accv[0] = __builtin_amdgcn_mfma_f32_32x32x16_bf16(ah, bl0, accv[0], 0, 0, 0);
            accv[1] = __builtin_amdgcn_mfma_f32_32x32x16_bf16(ah, bl1, accv[1], 0, 0, 0);
        }
    }
    #pragma unroll
    for (int ct = 0; ct < 2; ++ct) {
        int col = (ct << 5) + l31;
        #pragma unroll
        for (int r = 0; r < 16; ++r) {
            int row = rowbase + (w << 5) + (r & 3) + ((r >> 2) << 3) + (hl << 2);
            if (row < nrows) Cout[(size_t)row * 64 + col] = accv[ct][r];
        }
    }
}

// ---------------------------------------------------------------------------
// Feature epilogue: x = gelu(LN(y + lin_b)) + l2norm(emb)
// ---------------------------------------------------------------------------
__global__ __launch_bounds__(256) void k_feat_post(
    const float* __restrict__ y, const float* __restrict__ lin_b,
    const float* __restrict__ ln_g, const float* __restrict__ ln_b,
    const float* __restrict__ emb, float* __restrict__ xout)
{
    int n = (blockIdx.x << 2) + (threadIdx.x >> 6);
    int c = threadIdx.x & 63;
    size_t base = (size_t)n * 64 + c;
    float v = y[base] + lin_b[c];
    float mean = wave_sum64(v) * 0.015625f;
    float t = v - mean;
    float var = wave_sum64(t * t) * 0.015625f;
    float vn = t * (1.0f / sqrtf(var + 1e-5f)) * ln_g[c] + ln_b[c];
    float g = gelu_exact(vn);
    float e = emb[base];
    float nrm = sqrtf(wave_sum64(e * e));
    float xv = g + e / fmaxf(nrm, 1e-12f);
    xout[base] = xv;
}

// ---------------------------------------------------------------------------
// Edge-parallel softmax numerator over REAL edges: one lane = one CSR slot.
// p[t][e][h] = exp(leakyrelu(s_all[src][t*8+h] + s_all[dst][t*8+4+h]))
// ---------------------------------------------------------------------------
__global__ __launch_bounds__(256) void k_edgep(
    const float* __restrict__ s_all, const int2* __restrict__ sd,
    float* __restrict__ parr)
{
    int i = blockIdx.x * 256 + threadIdx.x;
    int t = blockIdx.y;
    if (i >= EE) return;
    size_t base = (size_t)t * EE + i;
    int2 e = sd[base];
    const float4 a = *(const float4*)&s_all[(size_t)e.x * 64 + t * 8];
    const float4 b = *(const float4*)&s_all[(size_t)e.y * 64 + t * 8 + 4];
    float l0 = a.x + b.x, l1 = a.y + b.y;
    float l2 = a.z + b.z, l3 = a.w + b.w;
    l0 = l0 > 0.f ? l0 : 0.2f * l0;
    l1 = l1 > 0.f ? l1 : 0.2f * l1;
    l2 = l2 > 0.f ? l2 : 0.2f * l2;
    l3 = l3 > 0.f ? l3 : 0.2f * l3;
    float4 p = make_float4(__expf(l0), __expf(l1), __expf(l2), __expf(l3));
    *(float4*)&parr[base * 4] = p;
}

// ---------------------------------------------------------------------------
// FUSED layer kernel (512 threads, 64 nodes/block, 64 KB LDS -> 2 blocks/CU):
// per type t:
//   (a) 8 waves aggregate 8 nodes each (two interleaved 4-node streams);
//       self-loop inline (verified round 7); v = z/S; split-bf16 -> LDS in
//       the XOR-granule layout (verified round 6)
//   (b) waves 0-3 MFMA one 32x32 C-quadrant each, K=256; B operand loaded
//       global->registers per k-chunk (B is L2-resident, no LDS/barriers)
// Epilogue: dest[row][col] = gelu((acc + bsum[col]) * 0.25).
// Only 2 barriers per type; z never touches HBM.
// ---------------------------------------------------------------------------
__global__ __launch_bounds__(512, 4) void k_fused(
    const float* __restrict__ x, const float* __restrict__ s_all,
    const float* __restrict__ parr, const int* __restrict__ row_ptr,
    const int2* __restrict__ sd,
    const ushort_t* __restrict__ Bh, const ushort_t* __restrict__ Bl,
    const float* __restrict__ bias, float* __restrict__ dest)
{
    __shared__ ushort_t zH[64 * 256], zL[64 * 256];   // 32 KB + 32 KB
    const int tid = threadIdx.x;
    const int w = tid >> 6, lane = tid & 63;
    const int l31 = lane & 31, hl = lane >> 5;
    const int rt = w >> 1, ct = w & 1;                // quadrant (waves 0-3)
    const int rowbase = blockIdx.x * 64;

    floatx16 acc;
    #pragma unroll
    for (int r = 0; r < 16; ++r) acc[r] = 0.f;

    for (int t = 0; t < TT; ++t) {
        if (t) __syncthreads();        // prev MFMA done before z overwrite
        // ---- (a) aggregate: 8 waves x 8 nodes (2 interleaved streams) ----
        const int*     srcs = (const int*)(sd + (size_t)t * EE);
        const floatx4* pt   = (const floatx4*)parr + (size_t)t * EE;
        const int* rp = row_ptr + t * (NN + 1);
        #pragma unroll 1
        for (int i = 0; i < 4; ++i) {
            int lrA = (w << 3) + i, lrB = lrA + 4;
            int nA = rowbase + lrA, nB = rowbase + lrB;
            float a0, a1, a2, a3, SA0, SA1, SA2, SA3;
            float b0, b1, b2, b3, SB0, SB1, SB2, SB3;
            int eA = 0, eA1 = 0, eB = 0, eB1 = 0;
            // self-loop init (verified round 7): p_self from s_all[n], x[n]
            if (nA < NN) {
                eA = rp[nA]; eA1 = rp[nA + 1];
                float xn = x[(size_t)nA * 64 + lane];
                const float4 sa = *(const float4*)&s_all[(size_t)nA * 64 + t * 8];
                const float4 sb = *(const float4*)&s_all[(size_t)nA * 64 + t * 8 + 4];
                float l0 = sa.x + sb.x, l1 = sa.y + sb.y;
                float l2 = sa.z + sb.z, l3 = sa.w + sb.w;
                l0 = l0 > 0.f ? l0 : 0.2f * l0;  l1 = l1 > 0.f ? l1 : 0.2f * l1;
                l2 = l2 > 0.f ? l2 : 0.2f * l2;  l3 = l3 > 0.f ? l3 : 0.2f * l3;
                SA0 = __expf(l0); SA1 = __expf(l1); SA2 = __expf(l2); SA3 = __expf(l3);
                a0 = SA0 * xn; a1 = SA1 * xn; a2 = SA2 * xn; a3 = SA3 * xn;
            } else {
                SA0 = SA1 = SA2 = SA3 = 1.f;
                a0 = a1 = a2 = a3 = 0.f;
            }
            if (nB < NN) {
                eB = rp[nB]; eB1 = rp[nB + 1];
                float xn = x[(size_t)nB * 64 + lane];
                const float4 sa = *(const float4*)&s_all[(size_t)nB * 64 + t * 8];
                const float4 sb = *(const float4*)&s_all[(size_t)nB * 64 + t * 8 + 4];
                float l0 = sa.x + sb.x, l1 = sa.y + sb.y;
                float l2 = sa.z + sb.z, l3 = sa.w + sb.w;
                l0 = l0 > 0.f ? l0 : 0.2f * l0;  l1 = l1 > 0.f ? l1 : 0.2f * l1;
                l2 = l2 > 0.f ? l2 : 0.2f * l2;  l3 = l3 > 0.f ? l3 : 0.2f * l3;
                SB0 = __expf(l0); SB1 = __expf(l1); SB2 = __expf(l2); SB3 = __expf(l3);
                b0 = SB0 * xn; b1 = SB1 * xn; b2 = SB2 * xn; b3 = SB3 * xn;
            } else {
                SB0 = SB1 = SB2 = SB3 = 1.f;
                b0 = b1 = b2 = b3 = 0.f;
            }
            int m = (eA1 - eA < eB1 - eB) ? (eA1 - eA) : (eB1 - eB);
            #pragma unroll 2
            for (int q = 0; q < m; ++q) {
                int sA_ = srcs[2 * (eA + q)];                 // wave-uniform
                int sB_ = srcs[2 * (eB + q)];
                floatx4 pa = pt[eA + q];                      // wave-uniform 16B
                floatx4 pb = pt[eB + q];
                float xa = x[(size_t)sA_ * 64 + lane];        // coalesced 256B
                float xb = x[(size_t)sB_ * 64 + lane];
                SA0 += pa.x; SA1 += pa.y; SA2 += pa.z; SA3 += pa.w;
                SB0 += pb.x; SB1 += pb.y; SB2 += pb.z; SB3 += pb.w;
                a0 = fmaf(pa.x, xa, a0); a1 = fmaf(pa.y, xa, a1);
                a2 = fmaf(pa.z, xa, a2); a3 = fmaf(pa.w, xa, a3);
                b0 = fmaf(pb.x, xb, b0); b1 = fmaf(pb.y, xb, b1);
                b2 = fmaf(pb.z, xb, b2); b3 = fmaf(pb.w, xb, b3);
            }
            eA += m; eB += m;
            for (; eA < eA1; ++eA) {
                int s = srcs[2 * eA]; floatx4 p = pt[eA];
                float xv = x[(size_t)s * 64 + lane];
                SA0 += p.x; SA1 += p.y; SA2 += p.z; SA3 += p.w;
                a0 = fmaf(p.x, xv, a0); a1 = fmaf(p.y, xv, a1);
                a2 = fmaf(p.z, xv, a2); a3 = fmaf(p.w, xv, a3);
            }
            for (; eB < eB1; ++eB) {
                int s = srcs[2 * eB]; floatx4 p = pt[eB];
                float xv = x[(size_t)s * 64 + lane];
                SB0 += p.x; SB1 += p.y; SB2 += p.z; SB3 += p.w;
                b0 = fmaf(p.x, xv, b0); b1 = fmaf(p.y, xv, b1);
                b2 = fmaf(p.z, xv, b2); b3 = fmaf(p.w, xv, b3);
            }
            // convert + LDS write, XOR-granule layout (verified round 6):
            // k = d*4+h; lane d writes 4 shorts (8B) per plane
            {
                int gsw = ((lane >> 1) ^ (lrA & 31)) << 3;
                int go = lrA * 256 + gsw + ((lane & 1) << 2);
                float v0 = a0 / SA0, v1 = a1 / SA1, v2 = a2 / SA2, v3 = a3 / SA3;
                unsigned h0 = f2bf(v0), h1 = f2bf(v1), h2 = f2bf(v2), h3 = f2bf(v3);
                *(uint2*)&zH[go] = make_uint2(h0 | (h1 << 16), h2 | (h3 << 16));
                unsigned q0 = f2bf(v0 - bf2f((ushort_t)h0));
                unsigned q1 = f2bf(v1 - bf2f((ushort_t)h1));
                unsigned q2 = f2bf(v2 - bf2f((ushort_t)h2));
                unsigned q3 = f2bf(v3 - bf2f((ushort_t)h3));
                *(uint2*)&zL[go] = make_uint2(q0 | (q1 << 16), q2 | (q3 << 16));
            }
            {
                int gsw = ((lane >> 1) ^ (lrB & 31)) << 3;
                int go = lrB * 256 + gsw + ((lane & 1) << 2);
                float v0 = b0 / SB0, v1 = b1 / SB1, v2 = b2 / SB2, v3 = b3 / SB3;
                unsigned h0 = f2bf(v0), h1 = f2bf(v1), h2 = f2bf(v2), h3 = f2bf(v3);
                *(uint2*)&zH[go] = make_uint2(h0 | (h1 << 16), h2 | (h3 << 16));
                unsigned q0 = f2bf(v0 - bf2f((ushort_t)h0));
                unsigned q1 = f2bf(v1 - bf2f((ushort_t)h1));
                unsigned q2 = f2bf(v2 - bf2f((ushort_t)h2));
                unsigned q3 = f2bf(v3 - bf2f((ushort_t)h3));
                *(uint2*)&zL[go] = make_uint2(q0 | (q1 << 16), q2 | (q3 << 16));
            }
        }
        __syncthreads();               // z tile ready
        // ---- (b) MFMA: waves 0-3, one C-quadrant each, K=256; B from L2 ----
        if (w < 4) {
            const int am = (rt << 5) + l31;
            const ushort_t* Bht = Bh + (size_t)((ct << 5) + l31) * 1024 + t * 256;
            const ushort_t* Blt = Bl + (size_t)((ct << 5) + l31) * 1024 + t * 256;
            #pragma unroll
            for (int kc = 0; kc < 8; ++kc) {
                #pragma unroll
                for (int s = 0; s < 2; ++s) {
                    int gg = kc * 4 + (s << 1) + hl;
                    int ao = am * 256 + ((gg ^ (am & 31)) << 3);
                    bf16x8 ah = *(const bf16x8*)&zH[ao];
                    bf16x8 al = *(const bf16x8*)&zL[ao];
                    int kb = kc * 32 + ((s << 1) | hl) * 8;
                    bf16x8 bh = *(const bf16x8*)(Bht + kb);
                    bf16x8 bl = *(const bf16x8*)(Blt + kb);
                    acc = __builtin_amdgcn_mfma_f32_32x32x16_bf16(ah, bh, acc, 0, 0, 0);
                    acc = __builtin_amdgcn_mfma_f32_32x32x16_bf16(al, bh, acc, 0, 0, 0);
                    acc = __builtin_amdgcn_mfma_f32_32x32x16_bf16(ah, bl, acc, 0, 0, 0);
                }
            }
        }
    }
    // ---- epilogue: bias + gelu (C/D layout verified round 6) ----
    if (w < 4) {
        int col = (ct << 5) + l31;
        float bv = bias[col];
        #pragma unroll
        for (int r = 0; r < 16; ++r) {
            int row = rowbase + (rt << 5) + (r & 3) + ((r >> 2) << 3) + (hl << 2);
            if (row < NN)
                dest[(size_t)row * 64 + col] = gelu_exact((acc[r] + bv) * 0.25f);
        }
    }
}

// ---------------------------------------------------------------------------
extern "C" void kernel_launch(void* const* d_in, const int* in_sizes, int n_in,
                              void* d_out, int out_size, void* d_ws, size_t ws_size,
                              hipStream_t stream) {
    const float* fm    = (const float*)d_in[0];
    const float* emb   = (const float*)d_in[1];
    const float* lin_w = (const float*)d_in[2];
    const float* lin_b = (const float*)d_in[3];
    const float* ln_g  = (const float*)d_in[4];
    const float* ln_b  = (const float*)d_in[5];
    const float* Wsrc  = (const float*)d_in[6];
    const float* Wdst  = (const float*)d_in[7];
    const float* asrc  = (const float*)d_in[8];
    const float* adst  = (const float*)d_in[9];
    const float* cbias = (const float*)d_in[10];
    const int*   ei    = (const int*)d_in[11];
    float* out = (float*)d_out;
    (void)in_sizes; (void)n_in; (void)out_size; (void)ws_size;

    char* w = (char*)d_ws;
    size_t off = 0;
    auto alloc = [&](size_t bytes) -> void* {
        void* p = w + off;
        off += (bytes + 255) & ~(size_t)255;
        return p;
    };
    ushort_t* wcTh = (ushort_t*)alloc((size_t)LL * 64 * 64 * 2);
    ushort_t* wcTl = (ushort_t*)alloc((size_t)LL * 64 * 64 * 2);
    ushort_t* lwTh = (ushort_t*)alloc((size_t)64 * 256 * 2);
    ushort_t* lwTl = (ushort_t*)alloc((size_t)64 * 256 * 2);
    ushort_t* bpTh = (ushort_t*)alloc((size_t)LL * 64 * 1024 * 2);
    ushort_t* bpTl = (ushort_t*)alloc((size_t)LL * 64 * 1024 * 2);
    float* bsum    = (float*)alloc((size_t)LL * 64 * 4);
    int*   row_ptr = (int*)  alloc((size_t)TT * (NN + 1) * 4);
    int*   cursor  = (int*)  alloc((size_t)TT * NN * 4);
    int2*  sdarr   = (int2*) alloc((size_t)TT * EE * 8);
    float* parr    = (float*)alloc((size_t)TT * EE * 4 * 4);
    int*   csum    = (int*)  alloc((size_t)TT * NCH * 4);
    int*   cbase   = (int*)  alloc((size_t)TT * NCH * 4);
    float* x       = (float*)alloc(N64 * 4);
    float* xnew    = (float*)alloc(N64 * 4);
    float* s_all   = (float*)alloc(N64 * 4);
    float* ybuf    = (float*)alloc(N64 * 4);

    hipMemsetAsync(cursor, 0, (size_t)TT * NN * 4, stream);
    k_prep<<<512, 256, 0, stream>>>(Wsrc, Wdst, asrc, adst, cbias, lin_w,
                                    wcTh, wcTl, lwTh, lwTl, bpTh, bpTl, bsum);
    k_hist<<<(TT * EE + 255) / 256, 256, 0, stream>>>(ei, cursor);
    k_scan1<<<TT * NCH, 256, 0, stream>>>(cursor, csum);
    k_scan2<<<1, 64, 0, stream>>>(csum, cbase, row_ptr);
    k_scan3<<<TT * NCH, 256, 0, stream>>>(cursor, cbase, row_ptr);
    k_scatter<<<(TT * EE + 255) / 256, 256, 0, stream>>>(ei, cursor, sdarr);

    const int GB = (NN + 127) / 128;   // 782 blocks (128 rows each)
    // feature transform: GEMM K=256 (fp32 A, split fused into staging)
    k_gemm_f32a<<<GB, 256, 0, stream>>>(fm, lwTh, lwTl, 256, 256, NN, ybuf);
    k_feat_post<<<NN / 4, 256, 0, stream>>>(ybuf, lin_b, ln_g, ln_b, emb, x);

    const dim3 gp((EE + 255) / 256, TT);
    const int FB = (NN + 63) / 64;     // 1563 fused blocks
    for (int l = 0; l < LL; ++l) {
        const float* xin = (l == 0) ? x : xnew;
        float* dest = (l == 0) ? xnew : out;
        // collapsed attention-logit projection: s_all = xin @ wcoll_l  [N,64]
        k_gemm_f32a<<<GB, 256, 0, stream>>>(xin, wcTh + l * 4096, wcTl + l * 4096,
                                            64, 64, NN, s_all);
        // edge-parallel p = exp(leaky(logit)) over real edges, all 4 types
        k_edgep<<<gp, 256, 0, stream>>>(s_all, sdarr, parr);
        // fused: aggregate z into LDS + project + bias + gelu -> dest
        k_fused<<<FB, 512, 0, stream>>>(xin, s_all, parr, row_ptr, sdarr,
                                        bpTh + (size_t)l * 65536,
                                        bpTl + (size_t)l * 65536,
                                        bsum + l * 64, dest);
    }
}

// Round 9
// 1020.815 us; speedup vs baseline: 1.0308x; 1.0308x over previous
//
#include <hip/hip_runtime.h>
#include <hip/hip_bf16.h>
#include <cstdint>

#define NN   100000
#define TT   4
#define EE   250000
#define LL   2
#define NCH  49            // ceil(NN/2048)
#define N64  ((size_t)NN * 64)

typedef unsigned short ushort_t;
typedef __attribute__((ext_vector_type(8))) short bf16x8;
typedef __attribute__((ext_vector_type(16))) float floatx16;
typedef __attribute__((ext_vector_type(4))) float floatx4;

static __device__ __forceinline__ float gelu_exact(float v) {
    return 0.5f * v * (1.0f + erff(v * 0.7071067811865476f));
}
static __device__ __forceinline__ float wave_sum64(float v) {
    #pragma unroll
    for (int m = 32; m; m >>= 1) v += __shfl_xor(v, m, 64);
    return v;
}
// fp32 -> bf16 round-to-nearest-even (finite inputs only)
static __device__ __forceinline__ ushort_t f2bf(float f) {
    unsigned u = __float_as_uint(f);
    u += 0x7FFFu + ((u >> 16) & 1u);
    return (ushort_t)(u >> 16);
}
static __device__ __forceinline__ float bf2f(ushort_t h) {
    return __uint_as_float((unsigned)h << 16);
}
// async global->LDS 16B (per-lane global addr; LDS dest = wave base + lane*16)
static __device__ __forceinline__ void gl_lds16(const ushort_t* g, ushort_t* l) {
    __builtin_amdgcn_global_load_lds(
        (const __attribute__((address_space(1))) void*)g,
        (__attribute__((address_space(3))) void*)l, 16, 0, 0);
}

// ---------------------------------------------------------------------------
// Prep: GEMM B-operands as TRANSPOSED split-bf16 planes [n][k]:
//  wcollT[l][col][d]  (K=64)   col = t*8+side*4+h, from W·a dot products
//  linwT[c][k]        (K=256)  from lin_w[k][c]
//  bprojT[l][c][kidx] (K=1024) kidx = t*256+h*64+d, val 0.25*W_src[l,t,d,h*64+c]
//  bsum[l][c] = sum_t conv_bias
// ---------------------------------------------------------------------------
__global__ __launch_bounds__(256) void k_prep(
    const float* __restrict__ Wsrc, const float* __restrict__ Wdst,
    const float* __restrict__ asrc, const float* __restrict__ adst,
    const float* __restrict__ cb, const float* __restrict__ lin_w,
    ushort_t* __restrict__ wcTh, ushort_t* __restrict__ wcTl,
    ushort_t* __restrict__ lwTh, ushort_t* __restrict__ lwTl,
    ushort_t* __restrict__ bpTh, ushort_t* __restrict__ bpTl,
    float* __restrict__ bsum)
{
    int id = blockIdx.x * 256 + threadIdx.x;   // grid = 131072 exactly
    {   // bprojT: id = ((((l*4+t)*4+h)*64 + c)*64 + d)
        int d = id & 63;
        int c = (id >> 6) & 63;
        int h = (id >> 12) & 3;
        int t = (id >> 14) & 3;
        int l = (id >> 16) & 1;
        float v = 0.25f * Wsrc[(((l * 4 + t) * 64 + d) * 256) + h * 64 + c];
        int dst = (l * 64 + c) * 1024 + (t * 256 + h * 64 + d);
        ushort_t hh = f2bf(v);
        bpTh[dst] = hh;
        bpTl[dst] = f2bf(v - bf2f(hh));
    }
    if (id < LL * 64 * 64) {   // wcollT
        int d   = id & 63;
        int col = (id >> 6) & 63;
        int l   = (id >> 12) & 1;
        int t = col >> 3, side = (col >> 2) & 1, h = col & 3;
        const float* W = side ? Wdst : Wsrc;
        const float* a = side ? adst : asrc;
        int wb = ((l * 4 + t) * 64 + d) * 256 + h * 64;
        int ab = ((l * 4 + t) * 4 + h) * 64;
        float s = 0.f;
        #pragma unroll 8
        for (int c2 = 0; c2 < 64; ++c2) s = fmaf(W[wb + c2], a[ab + c2], s);
        int dst = (l * 64 + col) * 64 + d;
        ushort_t hh = f2bf(s);
        wcTh[dst] = hh;
        wcTl[dst] = f2bf(s - bf2f(hh));
    }
    if (id < 64 * 256) {       // linwT: c = id>>8, k = id&255
        int k = id & 255, c = id >> 8;
        float v = lin_w[k * 64 + c];
        ushort_t hh = f2bf(v);
        lwTh[c * 256 + k] = hh;
        lwTl[c * 256 + k] = f2bf(v - bf2f(hh));
    }
    if (id < LL * 64) {        // bias_sum
        int l = id >> 6, c = id & 63;
        float s = 0.f;
        for (int t = 0; t < TT; ++t) s += cb[(l * 4 + t) * 64 + c];
        bsum[id] = s;
    }
}

// ---------------------------------------------------------------------------
// CSR build over REAL edges only (self-loops handled inline in k_edge2).
// ---------------------------------------------------------------------------
__global__ void k_hist(const int* __restrict__ ei, int* __restrict__ cursor) {
    int id = blockIdx.x * 256 + threadIdx.x;
    if (id >= TT * EE) return;
    int t = id / EE, e = id - t * EE;
    int d = ei[(t * 2 + 1) * EE + e];
    atomicAdd(&cursor[t * NN + d], 1);
}

__global__ __launch_bounds__(256) void k_scan1(const int* __restrict__ deg,
                                               int* __restrict__ csum) {
    int b = blockIdx.x, t = b / NCH, cc = b - t * NCH;
    int tid = threadIdx.x;
    int base = cc * 2048 + tid * 8;
    int s = 0;
    #pragma unroll
    for (int i = 0; i < 8; ++i) {
        int idx = base + i;
        if (idx < NN) s += deg[t * NN + idx];       // real edges only
    }
    #pragma unroll
    for (int m = 32; m; m >>= 1) s += __shfl_xor(s, m, 64);
    __shared__ int ws4[4];
    int lane = tid & 63, wid = tid >> 6;
    if (lane == 0) ws4[wid] = s;
    __syncthreads();
    if (tid == 0) csum[b] = ws4[0] + ws4[1] + ws4[2] + ws4[3];
}

__global__ void k_scan2(const int* __restrict__ csum, int* __restrict__ cbase,
                        int* __restrict__ row_ptr) {
    int t = threadIdx.x;
    if (t >= TT) return;
    int base = 0;
    for (int c = 0; c < NCH; ++c) {
        cbase[t * NCH + c] = base;
        base += csum[t * NCH + c];
    }
    row_ptr[t * (NN + 1) + NN] = base;   // = EE
}

__global__ __launch_bounds__(256) void k_scan3(int* __restrict__ cursor,
                                               const int* __restrict__ cbase,
                                               int* __restrict__ row_ptr) {
    int b = blockIdx.x, t = b / NCH, cc = b - t * NCH;
    int tid = threadIdx.x, lane = tid & 63, wid = tid >> 6;
    int base = cc * 2048 + tid * 8;
    int vals[8], ts = 0;
    #pragma unroll
    for (int i = 0; i < 8; ++i) {
        int idx = base + i;
        int v = (idx < NN) ? cursor[t * NN + idx] : 0;   // no self slot
        vals[i] = v; ts += v;
    }
    int v = ts;
    #pragma unroll
    for (int off = 1; off < 64; off <<= 1) {
        int u = __shfl_up(v, off, 64);
        if (lane >= off) v += u;
    }
    __shared__ int wt[4];
    if (lane == 63) wt[wid] = v;
    __syncthreads();
    int wbase = 0;
    for (int w = 0; w < wid; ++w) wbase += wt[w];
    int run = cbase[t * NCH + cc] + wbase + (v - ts);
    #pragma unroll
    for (int i = 0; i < 8; ++i) {
        int idx = base + i;
        if (idx < NN) {
            row_ptr[t * (NN + 1) + idx] = run;
            cursor[t * NN + idx] = run;     // becomes scatter write-head
        }
        run += vals[i];
    }
}

__global__ void k_scatter(const int* __restrict__ ei, int* __restrict__ cursor,
                          int2* __restrict__ sd) {
    int id = blockIdx.x * 256 + threadIdx.x;
    if (id >= TT * EE) return;
    int t = id / EE, r = id - t * EE;
    int s = ei[t * 2 * EE + r];
    int d = ei[(t * 2 + 1) * EE + r];
    int pos = atomicAdd(&cursor[t * NN + d], 1);
    sd[(size_t)t * EE + pos] = make_int2(s, d);
}

// ---------------------------------------------------------------------------
// Split-bf16 MFMA GEMM, fp32 A (feature transform + s_all projection).
// C[N,64] = A[N,K] @ B[K,64]; A split into hi/lo during LDS staging.
// LDS: linear 64B rows, XOR chunk-swizzle applied on the source side.
// Fragment layouts (verified m74/m101/m120-lineage):
//   A[m][k]: m=lane&31, k=(lane>>5)*8+j    B[k][n]: n=lane&31, same k
//   C/D: col=lane&31 (+32*ct), row=(reg&3)+8*(reg>>2)+4*(lane>>5)
// ---------------------------------------------------------------------------
__global__ __launch_bounds__(256, 4) void k_gemm_f32a(
    const float* __restrict__ Af,
    const ushort_t* __restrict__ Bhi, const ushort_t* __restrict__ Blo,
    int K, int ldb, int nrows, float* __restrict__ Cout)
{
    constexpr int KC = 32;
    __shared__ ushort_t sAh[128 * 32], sAl[128 * 32];
    __shared__ ushort_t sBh[64 * 32],  sBl[64 * 32];
    const int tid = threadIdx.x;
    const int w = tid >> 6, ln = tid & 63;
    const int l31 = ln & 31, hl = ln >> 5;
    const int rowbase = blockIdx.x * 128;

    floatx16 accv[2];
    #pragma unroll
    for (int ct = 0; ct < 2; ++ct)
        #pragma unroll
        for (int r = 0; r < 16; ++r) accv[ct][r] = 0.f;

    for (int kc = 0; kc < K; kc += KC) {
        __syncthreads();
        // stage A: 128 rows x 32 k (4 chunks of 8), fp32 -> split-bf16
        #pragma unroll
        for (int i = 0; i < 2; ++i) {
            int f = tid + i * 256;           // 0..511
            int r = f >> 2, cg = f & 3;
            int row = rowbase + r;
            int sg = (r ^ (r >> 2)) & 3;
            int sw = r * 32 + ((cg ^ sg) << 3);
            if (row < nrows) {
                size_t ga = (size_t)row * K + kc + cg * 8;
                floatx4 v0 = *(const floatx4*)(Af + ga);
                floatx4 v1 = *(const floatx4*)(Af + ga + 4);
                float vf[8] = {v0.x, v0.y, v0.z, v0.w, v1.x, v1.y, v1.z, v1.w};
                unsigned hu[8], lu[8];
                #pragma unroll
                for (int q = 0; q < 8; ++q) {
                    ushort_t hh = f2bf(vf[q]);
                    hu[q] = hh;
                    lu[q] = f2bf(vf[q] - bf2f(hh));
                }
                uint4 H = make_uint4(hu[0] | (hu[1] << 16), hu[2] | (hu[3] << 16),
                                     hu[4] | (hu[5] << 16), hu[6] | (hu[7] << 16));
                uint4 L = make_uint4(lu[0] | (lu[1] << 16), lu[2] | (lu[3] << 16),
                                     lu[4] | (lu[5] << 16), lu[6] | (lu[7] << 16));
                *(uint4*)&sAh[sw] = H;
                *(uint4*)&sAl[sw] = L;
            } else {
                *(uint4*)&sAh[sw] = make_uint4(0, 0, 0, 0);
                *(uint4*)&sAl[sw] = make_uint4(0, 0, 0, 0);
            }
        }
        // stage B: 64 n-rows x 32 k, both planes, direct-to-LDS
        {
            int r = tid >> 2, cg = tid & 3;
            int sg = (r ^ (r >> 2)) & 3;
            int so = r * 32 + (cg << 3);
            size_t gb = (size_t)r * ldb + kc + ((cg ^ sg) << 3);
            gl_lds16(Bhi + gb, &sBh[so]);
            gl_lds16(Blo + gb, &sBl[so]);
        }
        __syncthreads();
        const int arow = (w << 5) + l31;
        const int sga = (arow ^ (arow >> 2)) & 3;
        const int sgb = (l31 ^ (l31 >> 2)) & 3;
        #pragma unroll
        for (int s = 0; s < 2; ++s) {
            const int c0 = (s << 1) | hl;
            const int ka = (c0 ^ sga) << 3;
            const int kb = (c0 ^ sgb) << 3;
            bf16x8 ah  = *(const bf16x8*)&sAh[arow * 32 + ka];
            bf16x8 al  = *(const bf16x8*)&sAl[arow * 32 + ka];
            bf16x8 bh0 = *(const bf16x8*)&sBh[l31 * 32 + kb];
            bf16x8 bl0 = *(const bf16x8*)&sBl[l31 * 32 + kb];
            bf16x8 bh1 = *(const bf16x8*)&sBh[(32 + l31) * 32 + kb];
            bf16x8 bl1 = *(const bf16x8*)&sBl[(32 + l31) * 32 + kb];
            accv[0] = __builtin_amdgcn_mfma_f32_32x32x16_bf16(ah, bh0, accv[0], 0, 0, 0);
            accv[1] = __builtin_amdgcn_mfma_f32_32x32x16_bf16(ah, bh1, accv[1], 0, 0, 0);
            accv[0] = __builtin_amdgcn_mfma_f32_32x32x16_bf16(al, bh0, accv[0], 0, 0, 0);
            accv[1] = __builtin_amdgcn_mfma_f32_32x32x16_bf16(al, bh1, accv[1], 0, 0, 0);
            accv[0] = __builtin_amdgcn_mfma_f32_32x32x16_bf16(ah, bl0, accv[0], 0, 0, 0);
            accv[1] = __builtin_amdgcn_mfma_f32_32x32x16_bf16(ah, bl1, accv[1], 0, 0, 0);
        }
    }
    #pragma unroll
    for (int ct = 0; ct < 2; ++ct) {
        int col = (ct << 5) + l31;
        #pragma unroll
        for (int r = 0; r < 16; ++r) {
            int row = rowbase + (w << 5) + (r & 3) + ((r >> 2) << 3) + (hl << 2);
            if (row < nrows) Cout[(size_t)row * 64 + col] = accv[ct][r];
        }
    }
}

// ---------------------------------------------------------------------------
// 64-row-tile GEMM for the z projection, fp32 A (split into hi/lo planes in
// registers during staging — bit-identical to the former bf16-plane path).
// B: split-bf16 TRANSPOSED planes via global_load_lds (source-side swizzle).
// Wave layout: rt=w>>1 (row half), ct=w&1 (col half); one 32x32 acc per wave
// (layout verified round 6/7).  FLAGS bit0: +accbuf; bit1: gelu((v+bias)/4)
// ---------------------------------------------------------------------------
template <int FLAGS>
__global__ __launch_bounds__(256, 6) void k_gemm64f(
    const float* __restrict__ Af,
    const ushort_t* __restrict__ Bhi, const ushort_t* __restrict__ Blo,
    int K, int ldb, int nrows,
    const float* __restrict__ accbuf, const float* __restrict__ bias,
    float* __restrict__ Cout)
{
    constexpr int KC = 32;
    __shared__ ushort_t sAh[64 * 32], sAl[64 * 32];
    __shared__ ushort_t sBh[64 * 32], sBl[64 * 32];
    const int tid = threadIdx.x;
    const int w = tid >> 6, ln = tid & 63;
    const int l31 = ln & 31, hl = ln >> 5;
    const int rt = w >> 1, ct = w & 1;
    const int rowbase = blockIdx.x * 64;

    floatx16 acc;
    #pragma unroll
    for (int r = 0; r < 16; ++r) acc[r] = 0.f;

    for (int kc = 0; kc < K; kc += KC) {
        __syncthreads();
        {   // stage A (fp32 -> split) + B (direct-to-LDS), 64 rows each
            int r = tid >> 2, cg = tid & 3;
            int sg = (r ^ (r >> 2)) & 3;
            int row = rowbase + r;
            int sw = r * 32 + ((cg ^ sg) << 3);
            if (row < nrows) {
                size_t ga = (size_t)row * K + kc + cg * 8;
                floatx4 v0 = *(const floatx4*)(Af + ga);
                floatx4 v1 = *(const floatx4*)(Af + ga + 4);
                float vf[8] = {v0.x, v0.y, v0.z, v0.w, v1.x, v1.y, v1.z, v1.w};
                unsigned hu[8], lu[8];
                #pragma unroll
                for (int q = 0; q < 8; ++q) {
                    ushort_t hh = f2bf(vf[q]);
                    hu[q] = hh;
                    lu[q] = f2bf(vf[q] - bf2f(hh));
                }
                uint4 H = make_uint4(hu[0] | (hu[1] << 16), hu[2] | (hu[3] << 16),
                                     hu[4] | (hu[5] << 16), hu[6] | (hu[7] << 16));
                uint4 L = make_uint4(lu[0] | (lu[1] << 16), lu[2] | (lu[3] << 16),
                                     lu[4] | (lu[5] << 16), lu[6] | (lu[7] << 16));
                *(uint4*)&sAh[sw] = H;
                *(uint4*)&sAl[sw] = L;
            } else {
                *(uint4*)&sAh[sw] = make_uint4(0, 0, 0, 0);
                *(uint4*)&sAl[sw] = make_uint4(0, 0, 0, 0);
            }
            int so = r * 32 + (cg << 3);
            size_t gb = (size_t)r * ldb + kc + ((cg ^ sg) << 3);
            gl_lds16(Bhi + gb, &sBh[so]);
            gl_lds16(Blo + gb, &sBl[so]);
        }
        __syncthreads();
        const int arow = (rt << 5) + l31;
        const int brow = (ct << 5) + l31;
        const int sga = (arow ^ (arow >> 2)) & 3;
        const int sgb = (l31 ^ (l31 >> 2)) & 3;
        #pragma unroll
        for (int s = 0; s < 2; ++s) {
            const int c0 = (s << 1) | hl;
            const int ka = (c0 ^ sga) << 3;
            const int kb = (c0 ^ sgb) << 3;
            bf16x8 ah = *(const bf16x8*)&sAh[arow * 32 + ka];
            bf16x8 al = *(const bf16x8*)&sAl[arow * 32 + ka];
            bf16x8 bh = *(const bf16x8*)&sBh[brow * 32 + kb];
            bf16x8 bl = *(const bf16x8*)&sBl[brow * 32 + kb];
            acc = __builtin_amdgcn_mfma_f32_32x32x16_bf16(ah, bh, acc, 0, 0, 0);
            acc = __builtin_amdgcn_mfma_f32_32x32x16_bf16(al, bh, acc, 0, 0, 0);
            acc = __builtin_amdgcn_mfma_f32_32x32x16_bf16(ah, bl, acc, 0, 0, 0);
        }
    }
    // epilogue (C/D layout verified round 6/7)
    int col = (ct << 5) + l31;
    float bv = (FLAGS & 2) ? bias[col] : 0.f;
    #pragma unroll
    for (int r = 0; r < 16; ++r) {
        int row = rowbase + (rt << 5) + (r & 3) + ((r >> 2) << 3) + (hl << 2);
        if (row < nrows) {
            size_t idx = (size_t)row * 64 + col;
            float v = acc[r];
            if (FLAGS & 1) v += accbuf[idx];
            if (FLAGS & 2) v = gelu_exact((v + bv) * 0.25f);
            Cout[idx] = v;
        }
    }
}

// ---------------------------------------------------------------------------
// Feature epilogue: x = gelu(LN(y + lin_b)) + l2norm(emb)
// ---------------------------------------------------------------------------
__global__ __launch_bounds__(256) void k_feat_post(
    const float* __restrict__ y, const float* __restrict__ lin_b,
    const float* __restrict__ ln_g, const float* __restrict__ ln_b,
    const float* __restrict__ emb, float* __restrict__ xout)
{
    int n = (blockIdx.x << 2) + (threadIdx.x >> 6);
    int c = threadIdx.x & 63;
    size_t base = (size_t)n * 64 + c;
    float v = y[base] + lin_b[c];
    float mean = wave_sum64(v) * 0.015625f;
    float t = v - mean;
    float var = wave_sum64(t * t) * 0.015625f;
    float vn = t * (1.0f / sqrtf(var + 1e-5f)) * ln_g[c] + ln_b[c];
    float g = gelu_exact(vn);
    float e = emb[base];
    float nrm = sqrtf(wave_sum64(e * e));
    float xv = g + e / fmaxf(nrm, 1e-12f);
    xout[base] = xv;
}

// ---------------------------------------------------------------------------
// Edge-parallel softmax numerator over REAL edges: one lane = one CSR slot.
// p[t][e][h] = exp(leakyrelu(s_all[src][t*8+h] + s_all[dst][t*8+4+h]))
// ---------------------------------------------------------------------------
__global__ __launch_bounds__(256) void k_edgep(
    const float* __restrict__ s_all, const int2* __restrict__ sd,
    float* __restrict__ parr)
{
    int i = blockIdx.x * 256 + threadIdx.x;
    int t = blockIdx.y;
    if (i >= EE) return;
    size_t base = (size_t)t * EE + i;
    int2 e = sd[base];
    const float4 a = *(const float4*)&s_all[(size_t)e.x * 64 + t * 8];
    const float4 b = *(const float4*)&s_all[(size_t)e.y * 64 + t * 8 + 4];
    float l0 = a.x + b.x, l1 = a.y + b.y;
    float l2 = a.z + b.z, l3 = a.w + b.w;
    l0 = l0 > 0.f ? l0 : 0.2f * l0;
    l1 = l1 > 0.f ? l1 : 0.2f * l1;
    l2 = l2 > 0.f ? l2 : 0.2f * l2;
    l3 = l3 > 0.f ? l3 : 0.2f * l3;
    float4 p = make_float4(__expf(l0), __expf(l1), __expf(l2), __expf(l3));
    *(float4*)&parr[base * 4] = p;
}

// ---------------------------------------------------------------------------
// Edge aggregation for a TYPE PAIR (t0,t0+1) -> fp32 z [N][512].
// FOUR independent gather streams per wave: nodes (id, id+NN/2) x both types
// -> 4 outstanding src->x[src] chains (latency-bound loop).  Self-loops
// inline (verified round 7).  Grid = NN/8 blocks exactly.
// z[n][tt*256+h*64+d] = (p_self*x[n,d] + sum_e p_e,h*x[src_e,d]) / S[n,h]
// ---------------------------------------------------------------------------
__global__ __launch_bounds__(256, 6) void k_edge2(
    const float* __restrict__ x, const float* __restrict__ s_all,
    const float* __restrict__ parr, const int* __restrict__ row_ptr,
    const int2* __restrict__ sd, float* __restrict__ zf, int t0)
{
    int id = (blockIdx.x << 2) + (threadIdx.x >> 6);   // 0..NN/2-1
    int lane = threadIdx.x & 63;
    const int nA = id, nC = id + (NN / 2);
    const int tA = t0, tB = t0 + 1;
    int eA = row_ptr[tA * (NN + 1) + nA], eA1 = row_ptr[tA * (NN + 1) + nA + 1];
    int eB = row_ptr[tB * (NN + 1) + nA], eB1 = row_ptr[tB * (NN + 1) + nA + 1];
    int eC = row_ptr[tA * (NN + 1) + nC], eC1 = row_ptr[tA * (NN + 1) + nC + 1];
    int eD = row_ptr[tB * (NN + 1) + nC], eD1 = row_ptr[tB * (NN + 1) + nC + 1];
    const int*     sAp = (const int*)(sd + (size_t)tA * EE);   // .x at stride 2
    const floatx4* pAp = (const floatx4*)parr + (size_t)tA * EE;
    const int*     sBp = (const int*)(sd + (size_t)tB * EE);
    const floatx4* pBp = (const floatx4*)parr + (size_t)tB * EE;

    float xnA = x[(size_t)nA * 64 + lane];
    float xnC = x[(size_t)nC * 64 + lane];

    float a0, a1, a2, a3, SA0, SA1, SA2, SA3;
    float b0, b1, b2, b3, SB0, SB1, SB2, SB3;
    float c0, c1, c2, c3, SC0, SC1, SC2, SC3;
    float d0, d1, d2, d3, SD0, SD1, SD2, SD3;
    {   // self-loop inits (verified round 7): p_self from s_all[n], x[n]
        const float4 sa = *(const float4*)&s_all[(size_t)nA * 64 + tA * 8];
        const float4 sb = *(const float4*)&s_all[(size_t)nA * 64 + tA * 8 + 4];
        float l0 = sa.x + sb.x, l1 = sa.y + sb.y;
        float l2 = sa.z + sb.z, l3 = sa.w + sb.w;
        l0 = l0 > 0.f ? l0 : 0.2f * l0;  l1 = l1 > 0.f ? l1 : 0.2f * l1;
        l2 = l2 > 0.f ? l2 : 0.2f * l2;  l3 = l3 > 0.f ? l3 : 0.2f * l3;
        SA0 = __expf(l0); SA1 = __expf(l1); SA2 = __expf(l2); SA3 = __expf(l3);
        a0 = SA0 * xnA; a1 = SA1 * xnA; a2 = SA2 * xnA; a3 = SA3 * xnA;
    }
    {
        const float4 sa = *(const float4*)&s_all[(size_t)nA * 64 + tB * 8];
        const float4 sb = *(const float4*)&s_all[(size_t)nA * 64 + tB * 8 + 4];
        float l0 = sa.x + sb.x, l1 = sa.y + sb.y;
        float l2 = sa.z + sb.z, l3 = sa.w + sb.w;
        l0 = l0 > 0.f ? l0 : 0.2f * l0;  l1 = l1 > 0.f ? l1 : 0.2f * l1;
        l2 = l2 > 0.f ? l2 : 0.2f * l2;  l3 = l3 > 0.f ? l3 : 0.2f * l3;
        SB0 = __expf(l0); SB1 = __expf(l1); SB2 = __expf(l2); SB3 = __expf(l3);
        b0 = SB0 * xnA; b1 = SB1 * xnA; b2 = SB2 * xnA; b3 = SB3 * xnA;
    }
    {
        const float4 sa = *(const float4*)&s_all[(size_t)nC * 64 + tA * 8];
        const float4 sb = *(const float4*)&s_all[(size_t)nC * 64 + tA * 8 + 4];
        float l0 = sa.x + sb.x, l1 = sa.y + sb.y;
        float l2 = sa.z + sb.z, l3 = sa.w + sb.w;
        l0 = l0 > 0.f ? l0 : 0.2f * l0;  l1 = l1 > 0.f ? l1 : 0.2f * l1;
        l2 = l2 > 0.f ? l2 : 0.2f * l2;  l3 = l3 > 0.f ? l3 : 0.2f * l3;
        SC0 = __expf(l0); SC1 = __expf(l1); SC2 = __expf(l2); SC3 = __expf(l3);
        c0 = SC0 * xnC; c1 = SC1 * xnC; c2 = SC2 * xnC; c3 = SC3 * xnC;
    }
    {
        const float4 sa = *(const float4*)&s_all[(size_t)nC * 64 + tB * 8];
        const float4 sb = *(const float4*)&s_all[(size_t)nC * 64 + tB * 8 + 4];
        float l0 = sa.x + sb.x, l1 = sa.y + sb.y;
        float l2 = sa.z + sb.z, l3 = sa.w + sb.w;
        l0 = l0 > 0.f ? l0 : 0.2f * l0;  l1 = l1 > 0.f ? l1 : 0.2f * l1;
        l2 = l2 > 0.f ? l2 : 0.2f * l2;  l3 = l3 > 0.f ? l3 : 0.2f * l3;
        SD0 = __expf(l0); SD1 = __expf(l1); SD2 = __expf(l2); SD3 = __expf(l3);
        d0 = SD0 * xnC; d1 = SD1 * xnC; d2 = SD2 * xnC; d3 = SD3 * xnC;
    }
    // 4-way interleaved main loop
    int m4a = (eA1 - eA < eB1 - eB) ? (eA1 - eA) : (eB1 - eB);
    int m4b = (eC1 - eC < eD1 - eD) ? (eC1 - eC) : (eD1 - eD);
    int m4 = (m4a < m4b) ? m4a : m4b;
    #pragma unroll 1
    for (int q = 0; q < m4; ++q) {
        int sA = sAp[2 * (eA + q)];                       // wave-uniform
        int sB = sBp[2 * (eB + q)];
        int sC = sAp[2 * (eC + q)];
        int sD = sBp[2 * (eD + q)];
        floatx4 pa = pAp[eA + q];                         // wave-uniform 16B
        floatx4 pb = pBp[eB + q];
        floatx4 pc = pAp[eC + q];
        floatx4 pd = pBp[eD + q];
        float xa = x[(size_t)sA * 64 + lane];             // coalesced 256B
        float xb = x[(size_t)sB * 64 + lane];
        float xc = x[(size_t)sC * 64 + lane];
        float xd = x[(size_t)sD * 64 + lane];
        SA0 += pa.x; SA1 += pa.y; SA2 += pa.z; SA3 += pa.w;
        SB0 += pb.x; SB1 += pb.y; SB2 += pb.z; SB3 += pb.w;
        SC0 += pc.x; SC1 += pc.y; SC2 += pc.z; SC3 += pc.w;
        SD0 += pd.x; SD1 += pd.y; SD2 += pd.z; SD3 += pd.w;
        a0 = fmaf(pa.x, xa, a0); a1 = fmaf(pa.y, xa, a1);
        a2 = fmaf(pa.z, xa, a2); a3 = fmaf(pa.w, xa, a3);
        b0 = fmaf(pb.x, xb, b0); b1 = fmaf(pb.y, xb, b1);
        b2 = fmaf(pb.z, xb, b2); b3 = fmaf(pb.w, xb, b3);
        c0 = fmaf(pc.x, xc, c0); c1 = fmaf(pc.y, xc, c1);
        c2 = fmaf(pc.z, xc, c2); c3 = fmaf(pc.w, xc, c3);
        d0 = fmaf(pd.x, xd, d0); d1 = fmaf(pd.y, xd, d1);
        d2 = fmaf(pd.z, xd, d2); d3 = fmaf(pd.w, xd, d3);
    }
    eA += m4; eB += m4; eC += m4; eD += m4;
    // pair tails (A,B) and (C,D)
    {
        int m2 = (eA1 - eA < eB1 - eB) ? (eA1 - eA) : (eB1 - eB);
        #pragma unroll 2
        for (int q = 0; q < m2; ++q) {
            int sA = sAp[2 * (eA + q)];
            int sB = sBp[2 * (eB + q)];
            floatx4 pa = pAp[eA + q];
            floatx4 pb = pBp[eB + q];
            float xa = x[(size_t)sA * 64 + lane];
            float xb = x[(size_t)sB * 64 + lane];
            SA0 += pa.x; SA1 += pa.y; SA2 += pa.z; SA3 += pa.w;
            SB0 += pb.x; SB1 += pb.y; SB2 += pb.z; SB3 += pb.w;
            a0 = fmaf(pa.x, xa, a0); a1 = fmaf(pa.y, xa, a1);
            a2 = fmaf(pa.z, xa, a2); a3 = fmaf(pa.w, xa, a3);
            b0 = fmaf(pb.x, xb, b0); b1 = fmaf(pb.y, xb, b1);
            b2 = fmaf(pb.z, xb, b2); b3 = fmaf(pb.w, xb, b3);
        }
        eA += m2; eB += m2;
    }
    {
        int m2 = (eC1 - eC < eD1 - eD) ? (eC1 - eC) : (eD1 - eD);
        #pragma unroll 2
        for (int q = 0; q < m2; ++q) {
            int sC = sAp[2 * (eC + q)];
            int sD = sBp[2 * (eD + q)];
            floatx4 pc = pAp[eC + q];
            floatx4 pd = pBp[eD + q];
            float xc = x[(size_t)sC * 64 + lane];
            float xd = x[(size_t)sD * 64 + lane];
            SC0 += pc.x; SC1 += pc.y; SC2 += pc.z; SC3 += pc.w;
            SD0 += pd.x; SD1 += pd.y; SD2 += pd.z; SD3 += pd.w;
            c0 = fmaf(pc.x, xc, c0); c1 = fmaf(pc.y, xc, c1);
            c2 = fmaf(pc.z, xc, c2); c3 = fmaf(pc.w, xc, c3);
            d0 = fmaf(pd.x, xd, d0); d1 = fmaf(pd.y, xd, d1);
            d2 = fmaf(pd.z, xd, d2); d3 = fmaf(pd.w, xd, d3);
        }
        eC += m2; eD += m2;
    }
    // single tails
    for (; eA < eA1; ++eA) {
        int s = sAp[2 * eA]; floatx4 p = pAp[eA];
        float xv = x[(size_t)s * 64 + lane];
        SA0 += p.x; SA1 += p.y; SA2 += p.z; SA3 += p.w;
        a0 = fmaf(p.x, xv, a0); a1 = fmaf(p.y, xv, a1);
        a2 = fmaf(p.z, xv, a2); a3 = fmaf(p.w, xv, a3);
    }
    for (; eB < eB1; ++eB) {
        int s = sBp[2 * eB]; floatx4 p = pBp[eB];
        float xv = x[(size_t)s * 64 + lane];
        SB0 += p.x; SB1 += p.y; SB2 += p.z; SB3 += p.w;
        b0 = fmaf(p.x, xv, b0); b1 = fmaf(p.y, xv, b1);
        b2 = fmaf(p.z, xv, b2); b3 = fmaf(p.w, xv, b3);
    }
    for (; eC < eC1; ++eC) {
        int s = sAp[2 * eC]; floatx4 p = pAp[eC];
        float xv = x[(size_t)s * 64 + lane];
        SC0 += p.x; SC1 += p.y; SC2 += p.z; SC3 += p.w;
        c0 = fmaf(p.x, xv, c0); c1 = fmaf(p.y, xv, c1);
        c2 = fmaf(p.z, xv, c2); c3 = fmaf(p.w, xv, c3);
    }
    for (; eD < eD1; ++eD) {
        int s = sBp[2 * eD]; floatx4 p = pBp[eD];
        float xv = x[(size_t)s * 64 + lane];
        SD0 += p.x; SD1 += p.y; SD2 += p.z; SD3 += p.w;
        d0 = fmaf(p.x, xv, d0); d1 = fmaf(p.y, xv, d1);
        d2 = fmaf(p.z, xv, d2); d3 = fmaf(p.w, xv, d3);
    }
    // fp32 z writes (split into bf16 planes later, in the GEMM staging)
    {
        size_t zb = (size_t)nA * 512 + lane;
        zf[zb]       = a0 / SA0;  zf[zb + 64]  = a1 / SA1;
        zf[zb + 128] = a2 / SA2;  zf[zb + 192] = a3 / SA3;
        zf[zb + 256] = b0 / SB0;  zf[zb + 320] = b1 / SB1;
        zf[zb + 384] = b2 / SB2;  zf[zb + 448] = b3 / SB3;
    }
    {
        size_t zb = (size_t)nC * 512 + lane;
        zf[zb]       = c0 / SC0;  zf[zb + 64]  = c1 / SC1;
        zf[zb + 128] = c2 / SC2;  zf[zb + 192] = c3 / SC3;
        zf[zb + 256] = d0 / SD0;  zf[zb + 320] = d1 / SD1;
        zf[zb + 384] = d2 / SD2;  zf[zb + 448] = d3 / SD3;
    }
}

// ---------------------------------------------------------------------------
extern "C" void kernel_launch(void* const* d_in, const int* in_sizes, int n_in,
                              void* d_out, int out_size, void* d_ws, size_t ws_size,
                              hipStream_t stream) {
    const float* fm    = (const float*)d_in[0];
    const float* emb   = (const float*)d_in[1];
    const float* lin_w = (const float*)d_in[2];
    const float* lin_b = (const float*)d_in[3];
    const float* ln_g  = (const float*)d_in[4];
    const float* ln_b  = (const float*)d_in[5];
    const float* Wsrc  = (const float*)d_in[6];
    const float* Wdst  = (const float*)d_in[7];
    const float* asrc  = (const float*)d_in[8];
    const float* adst  = (const float*)d_in[9];
    const float* cbias = (const float*)d_in[10];
    const int*   ei    = (const int*)d_in[11];
    float* out = (float*)d_out;
    (void)in_sizes; (void)n_in; (void)out_size; (void)ws_size;

    char* w = (char*)d_ws;
    size_t off = 0;
    auto alloc = [&](size_t bytes) -> void* {
        void* p = w + off;
        off += (bytes + 255) & ~(size_t)255;
        return p;
    };
    ushort_t* wcTh = (ushort_t*)alloc((size_t)LL * 64 * 64 * 2);
    ushort_t* wcTl = (ushort_t*)alloc((size_t)LL * 64 * 64 * 2);
    ushort_t* lwTh = (ushort_t*)alloc((size_t)64 * 256 * 2);
    ushort_t* lwTl = (ushort_t*)alloc((size_t)64 * 256 * 2);
    ushort_t* bpTh = (ushort_t*)alloc((size_t)LL * 64 * 1024 * 2);
    ushort_t* bpTl = (ushort_t*)alloc((size_t)LL * 64 * 1024 * 2);
    float* bsum    = (float*)alloc((size_t)LL * 64 * 4);
    int*   row_ptr = (int*)  alloc((size_t)TT * (NN + 1) * 4);
    int*   cursor  = (int*)  alloc((size_t)TT * NN * 4);
    int2*  sdarr   = (int2*) alloc((size_t)TT * EE * 8);
    float* parr    = (float*)alloc((size_t)TT * EE * 4 * 4);
    int*   csum    = (int*)  alloc((size_t)TT * NCH * 4);
    int*   cbase   = (int*)  alloc((size_t)TT * NCH * 4);
    float* x       = (float*)alloc(N64 * 4);
    float* s_all   = (float*)alloc(N64 * 4);
    float* accB    = (float*)alloc(N64 * 4);
    // fp32 z for one type pair: [N][512]  (204.8 MB, same bytes as before)
    float* zf = (float*)alloc((size_t)NN * 512 * 4);

    hipMemsetAsync(cursor, 0, (size_t)TT * NN * 4, stream);
    k_prep<<<512, 256, 0, stream>>>(Wsrc, Wdst, asrc, adst, cbias, lin_w,
                                    wcTh, wcTl, lwTh, lwTl, bpTh, bpTl, bsum);
    k_hist<<<(TT * EE + 255) / 256, 256, 0, stream>>>(ei, cursor);
    k_scan1<<<TT * NCH, 256, 0, stream>>>(cursor, csum);
    k_scan2<<<1, 64, 0, stream>>>(csum, cbase, row_ptr);
    k_scan3<<<TT * NCH, 256, 0, stream>>>(cursor, cbase, row_ptr);
    k_scatter<<<(TT * EE + 255) / 256, 256, 0, stream>>>(ei, cursor, sdarr);

    const int GB  = (NN + 127) / 128;  // 782 blocks (128 rows each)
    const int GB2 = (NN + 63) / 64;    // 1563 blocks (64 rows each)
    // feature transform: GEMM K=256 (fp32 A, split fused into staging)
    k_gemm_f32a<<<GB, 256, 0, stream>>>(fm, lwTh, lwTl, 256, 256, NN, accB);
    k_feat_post<<<NN / 4, 256, 0, stream>>>(accB, lin_b, ln_g, ln_b, emb, x);

    const dim3 gp((EE + 255) / 256, TT);
    for (int l = 0; l < LL; ++l) {
        float* dest = (l == 0) ? x : out;
        // collapsed attention-logit projection: s_all = x @ wcoll_l  [N,64]
        k_gemm_f32a<<<GB, 256, 0, stream>>>(x, wcTh + l * 4096, wcTl + l * 4096,
                                            64, 64, NN, s_all);
        // edge-parallel p = exp(leaky(logit)) over real edges, all 4 types
        k_edgep<<<gp, 256, 0, stream>>>(s_all, sdarr, parr);
        const ushort_t* Bh = bpTh + (size_t)l * 65536;
        const ushort_t* Bl = bpTl + (size_t)l * 65536;
        // pair 0 (types 0,1): aggregate (4-stream) + GEMM K=512 -> accB
        k_edge2<<<NN / 8, 256, 0, stream>>>(x, s_all, parr, row_ptr, sdarr, zf, 0);
        k_gemm64f<0><<<GB2, 256, 0, stream>>>(zf, Bh, Bl, 512, 1024, NN,
                                              nullptr, nullptr, accB);
        // pair 1 (types 2,3): aggregate + GEMM K=512 + acc + gelu -> dest
        k_edge2<<<NN / 8, 256, 0, stream>>>(x, s_all, parr, row_ptr, sdarr, zf, 2);
        k_gemm64f<3><<<GB2, 256, 0, stream>>>(zf, Bh + 512, Bl + 512, 512, 1024,
                                              NN, accB, bsum + l * 64, dest);
    }
}

// Round 10
// 969.274 us; speedup vs baseline: 1.0856x; 1.0532x over previous
//
#include <hip/hip_runtime.h>
#include <hip/hip_bf16.h>
#include <cstdint>

#define NN   100000
#define TT   4
#define EE   250000
#define LL   2
#define NCH  49            // ceil(NN/2048)
#define N64  ((size_t)NN * 64)

typedef unsigned short ushort_t;
typedef __attribute__((ext_vector_type(8))) short bf16x8;
typedef __attribute__((ext_vector_type(16))) float floatx16;
typedef __attribute__((ext_vector_type(4))) float floatx4;

static __device__ __forceinline__ float gelu_exact(float v) {
    return 0.5f * v * (1.0f + erff(v * 0.7071067811865476f));
}
static __device__ __forceinline__ float wave_sum64(float v) {
    #pragma unroll
    for (int m = 32; m; m >>= 1) v += __shfl_xor(v, m, 64);
    return v;
}
// fp32 -> bf16 round-to-nearest-even (finite inputs only)
static __device__ __forceinline__ ushort_t f2bf(float f) {
    unsigned u = __float_as_uint(f);
    u += 0x7FFFu + ((u >> 16) & 1u);
    return (ushort_t)(u >> 16);
}
static __device__ __forceinline__ float bf2f(ushort_t h) {
    return __uint_as_float((unsigned)h << 16);
}
// async global->LDS 16B (per-lane global addr; LDS dest = wave base + lane*16)
static __device__ __forceinline__ void gl_lds16(const ushort_t* g, ushort_t* l) {
    __builtin_amdgcn_global_load_lds(
        (const __attribute__((address_space(1))) void*)g,
        (__attribute__((address_space(3))) void*)l, 16, 0, 0);
}

// ---------------------------------------------------------------------------
// Prep: GEMM B-operands as TRANSPOSED split-bf16 planes [n][k]:
//  wcollT[l][col][d]  (K=64)   col = t*8+side*4+h, from W·a dot products
//  linwT[c][k]        (K=256)  from lin_w[k][c]
//  bprojT[l][c][kidx] (K=1024) kidx = t*256+h*64+d, val 0.25*W_src[l,t,d,h*64+c]
//  bsum[l][c] = sum_t conv_bias
// ---------------------------------------------------------------------------
__global__ __launch_bounds__(256) void k_prep(
    const float* __restrict__ Wsrc, const float* __restrict__ Wdst,
    const float* __restrict__ asrc, const float* __restrict__ adst,
    const float* __restrict__ cb, const float* __restrict__ lin_w,
    ushort_t* __restrict__ wcTh, ushort_t* __restrict__ wcTl,
    ushort_t* __restrict__ lwTh, ushort_t* __restrict__ lwTl,
    ushort_t* __restrict__ bpTh, ushort_t* __restrict__ bpTl,
    float* __restrict__ bsum)
{
    int id = blockIdx.x * 256 + threadIdx.x;   // grid = 131072 exactly
    {   // bprojT: id = ((((l*4+t)*4+h)*64 + c)*64 + d)
        int d = id & 63;
        int c = (id >> 6) & 63;
        int h = (id >> 12) & 3;
        int t = (id >> 14) & 3;
        int l = (id >> 16) & 1;
        float v = 0.25f * Wsrc[(((l * 4 + t) * 64 + d) * 256) + h * 64 + c];
        int dst = (l * 64 + c) * 1024 + (t * 256 + h * 64 + d);
        ushort_t hh = f2bf(v);
        bpTh[dst] = hh;
        bpTl[dst] = f2bf(v - bf2f(hh));
    }
    if (id < LL * 64 * 64) {   // wcollT
        int d   = id & 63;
        int col = (id >> 6) & 63;
        int l   = (id >> 12) & 1;
        int t = col >> 3, side = (col >> 2) & 1, h = col & 3;
        const float* W = side ? Wdst : Wsrc;
        const float* a = side ? adst : asrc;
        int wb = ((l * 4 + t) * 64 + d) * 256 + h * 64;
        int ab = ((l * 4 + t) * 4 + h) * 64;
        float s = 0.f;
        #pragma unroll 8
        for (int c2 = 0; c2 < 64; ++c2) s = fmaf(W[wb + c2], a[ab + c2], s);
        int dst = (l * 64 + col) * 64 + d;
        ushort_t hh = f2bf(s);
        wcTh[dst] = hh;
        wcTl[dst] = f2bf(s - bf2f(hh));
    }
    if (id < 64 * 256) {       // linwT: c = id>>8, k = id&255
        int k = id & 255, c = id >> 8;
        float v = lin_w[k * 64 + c];
        ushort_t hh = f2bf(v);
        lwTh[c * 256 + k] = hh;
        lwTl[c * 256 + k] = f2bf(v - bf2f(hh));
    }
    if (id < LL * 64) {        // bias_sum
        int l = id >> 6, c = id & 63;
        float s = 0.f;
        for (int t = 0; t < TT; ++t) s += cb[(l * 4 + t) * 64 + c];
        bsum[id] = s;
    }
}

// ---------------------------------------------------------------------------
// CSR build over REAL edges only (self-loops handled inline in k_edge2).
// ---------------------------------------------------------------------------
__global__ void k_hist(const int* __restrict__ ei, int* __restrict__ cursor) {
    int id = blockIdx.x * 256 + threadIdx.x;
    if (id >= TT * EE) return;
    int t = id / EE, e = id - t * EE;
    int d = ei[(t * 2 + 1) * EE + e];
    atomicAdd(&cursor[t * NN + d], 1);
}

__global__ __launch_bounds__(256) void k_scan1(const int* __restrict__ deg,
                                               int* __restrict__ csum) {
    int b = blockIdx.x, t = b / NCH, cc = b - t * NCH;
    int tid = threadIdx.x;
    int base = cc * 2048 + tid * 8;
    int s = 0;
    #pragma unroll
    for (int i = 0; i < 8; ++i) {
        int idx = base + i;
        if (idx < NN) s += deg[t * NN + idx];       // real edges only
    }
    #pragma unroll
    for (int m = 32; m; m >>= 1) s += __shfl_xor(s, m, 64);
    __shared__ int ws4[4];
    int lane = tid & 63, wid = tid >> 6;
    if (lane == 0) ws4[wid] = s;
    __syncthreads();
    if (tid == 0) csum[b] = ws4[0] + ws4[1] + ws4[2] + ws4[3];
}

__global__ void k_scan2(const int* __restrict__ csum, int* __restrict__ cbase,
                        int* __restrict__ row_ptr) {
    int t = threadIdx.x;
    if (t >= TT) return;
    int base = 0;
    for (int c = 0; c < NCH; ++c) {
        cbase[t * NCH + c] = base;
        base += csum[t * NCH + c];
    }
    row_ptr[t * (NN + 1) + NN] = base;   // = EE
}

__global__ __launch_bounds__(256) void k_scan3(int* __restrict__ cursor,
                                               const int* __restrict__ cbase,
                                               int* __restrict__ row_ptr) {
    int b = blockIdx.x, t = b / NCH, cc = b - t * NCH;
    int tid = threadIdx.x, lane = tid & 63, wid = tid >> 6;
    int base = cc * 2048 + tid * 8;
    int vals[8], ts = 0;
    #pragma unroll
    for (int i = 0; i < 8; ++i) {
        int idx = base + i;
        int v = (idx < NN) ? cursor[t * NN + idx] : 0;   // no self slot
        vals[i] = v; ts += v;
    }
    int v = ts;
    #pragma unroll
    for (int off = 1; off < 64; off <<= 1) {
        int u = __shfl_up(v, off, 64);
        if (lane >= off) v += u;
    }
    __shared__ int wt[4];
    if (lane == 63) wt[wid] = v;
    __syncthreads();
    int wbase = 0;
    for (int w = 0; w < wid; ++w) wbase += wt[w];
    int run = cbase[t * NCH + cc] + wbase + (v - ts);
    #pragma unroll
    for (int i = 0; i < 8; ++i) {
        int idx = base + i;
        if (idx < NN) {
            row_ptr[t * (NN + 1) + idx] = run;
            cursor[t * NN + idx] = run;     // becomes scatter write-head
        }
        run += vals[i];
    }
}

__global__ void k_scatter(const int* __restrict__ ei, int* __restrict__ cursor,
                          int2* __restrict__ sd) {
    int id = blockIdx.x * 256 + threadIdx.x;
    if (id >= TT * EE) return;
    int t = id / EE, r = id - t * EE;
    int s = ei[t * 2 * EE + r];
    int d = ei[(t * 2 + 1) * EE + r];
    int pos = atomicAdd(&cursor[t * NN + d], 1);
    sd[(size_t)t * EE + pos] = make_int2(s, d);
}

// ---------------------------------------------------------------------------
// Split-bf16 MFMA GEMM, fp32 A (feature transform + s_all projection).
// C[N,64] = A[N,K] @ B[K,64]; A split into hi/lo during LDS staging.
// LDS: linear 64B rows, XOR chunk-swizzle applied on the source side.
// Fragment layouts (verified m74/m101/m120-lineage):
//   A[m][k]: m=lane&31, k=(lane>>5)*8+j    B[k][n]: n=lane&31, same k
//   C/D: col=lane&31 (+32*ct), row=(reg&3)+8*(reg>>2)+4*(lane>>5)
// ---------------------------------------------------------------------------
__global__ __launch_bounds__(256, 4) void k_gemm_f32a(
    const float* __restrict__ Af,
    const ushort_t* __restrict__ Bhi, const ushort_t* __restrict__ Blo,
    int K, int ldb, int nrows, float* __restrict__ Cout)
{
    constexpr int KC = 32;
    __shared__ ushort_t sAh[128 * 32], sAl[128 * 32];
    __shared__ ushort_t sBh[64 * 32],  sBl[64 * 32];
    const int tid = threadIdx.x;
    const int w = tid >> 6, ln = tid & 63;
    const int l31 = ln & 31, hl = ln >> 5;
    const int rowbase = blockIdx.x * 128;

    floatx16 accv[2];
    #pragma unroll
    for (int ct = 0; ct < 2; ++ct)
        #pragma unroll
        for (int r = 0; r < 16; ++r) accv[ct][r] = 0.f;

    for (int kc = 0; kc < K; kc += KC) {
        __syncthreads();
        // stage A: 128 rows x 32 k (4 chunks of 8), fp32 -> split-bf16
        #pragma unroll
        for (int i = 0; i < 2; ++i) {
            int f = tid + i * 256;           // 0..511
            int r = f >> 2, cg = f & 3;
            int row = rowbase + r;
            int sg = (r ^ (r >> 2)) & 3;
            int sw = r * 32 + ((cg ^ sg) << 3);
            if (row < nrows) {
                size_t ga = (size_t)row * K + kc + cg * 8;
                floatx4 v0 = *(const floatx4*)(Af + ga);
                floatx4 v1 = *(const floatx4*)(Af + ga + 4);
                float vf[8] = {v0.x, v0.y, v0.z, v0.w, v1.x, v1.y, v1.z, v1.w};
                unsigned hu[8], lu[8];
                #pragma unroll
                for (int q = 0; q < 8; ++q) {
                    ushort_t hh = f2bf(vf[q]);
                    hu[q] = hh;
                    lu[q] = f2bf(vf[q] - bf2f(hh));
                }
                uint4 H = make_uint4(hu[0] | (hu[1] << 16), hu[2] | (hu[3] << 16),
                                     hu[4] | (hu[5] << 16), hu[6] | (hu[7] << 16));
                uint4 L = make_uint4(lu[0] | (lu[1] << 16), lu[2] | (lu[3] << 16),
                                     lu[4] | (lu[5] << 16), lu[6] | (lu[7] << 16));
                *(uint4*)&sAh[sw] = H;
                *(uint4*)&sAl[sw] = L;
            } else {
                *(uint4*)&sAh[sw] = make_uint4(0, 0, 0, 0);
                *(uint4*)&sAl[sw] = make_uint4(0, 0, 0, 0);
            }
        }
        // stage B: 64 n-rows x 32 k, both planes, direct-to-LDS
        {
            int r = tid >> 2, cg = tid & 3;
            int sg = (r ^ (r >> 2)) & 3;
            int so = r * 32 + (cg << 3);
            size_t gb = (size_t)r * ldb + kc + ((cg ^ sg) << 3);
            gl_lds16(Bhi + gb, &sBh[so]);
            gl_lds16(Blo + gb, &sBl[so]);
        }
        __syncthreads();
        const int arow = (w << 5) + l31;
        const int sga = (arow ^ (arow >> 2)) & 3;
        const int sgb = (l31 ^ (l31 >> 2)) & 3;
        #pragma unroll
        for (int s = 0; s < 2; ++s) {
            const int c0 = (s << 1) | hl;
            const int ka = (c0 ^ sga) << 3;
            const int kb = (c0 ^ sgb) << 3;
            bf16x8 ah  = *(const bf16x8*)&sAh[arow * 32 + ka];
            bf16x8 al  = *(const bf16x8*)&sAl[arow * 32 + ka];
            bf16x8 bh0 = *(const bf16x8*)&sBh[l31 * 32 + kb];
            bf16x8 bl0 = *(const bf16x8*)&sBl[l31 * 32 + kb];
            bf16x8 bh1 = *(const bf16x8*)&sBh[(32 + l31) * 32 + kb];
            bf16x8 bl1 = *(const bf16x8*)&sBl[(32 + l31) * 32 + kb];
            accv[0] = __builtin_amdgcn_mfma_f32_32x32x16_bf16(ah, bh0, accv[0], 0, 0, 0);
            accv[1] = __builtin_amdgcn_mfma_f32_32x32x16_bf16(ah, bh1, accv[1], 0, 0, 0);
            accv[0] = __builtin_amdgcn_mfma_f32_32x32x16_bf16(al, bh0, accv[0], 0, 0, 0);
            accv[1] = __builtin_amdgcn_mfma_f32_32x32x16_bf16(al, bh1, accv[1], 0, 0, 0);
            accv[0] = __builtin_amdgcn_mfma_f32_32x32x16_bf16(ah, bl0, accv[0], 0, 0, 0);
            accv[1] = __builtin_amdgcn_mfma_f32_32x32x16_bf16(ah, bl1, accv[1], 0, 0, 0);
        }
    }
    #pragma unroll
    for (int ct = 0; ct < 2; ++ct) {
        int col = (ct << 5) + l31;
        #pragma unroll
        for (int r = 0; r < 16; ++r) {
            int row = rowbase + (w << 5) + (r & 3) + ((r >> 2) << 3) + (hl << 2);
            if (row < nrows) Cout[(size_t)row * 64 + col] = accv[ct][r];
        }
    }
}

// ---------------------------------------------------------------------------
// 64-row-tile GEMM for the z projection, fp32 A (split into hi/lo planes in
// registers during staging — bit-identical to the bf16-plane path).
// B: split-bf16 TRANSPOSED planes via global_load_lds (source-side swizzle).
// Wave layout: rt=w>>1 (row half), ct=w&1 (col half); one 32x32 acc per wave
// (layout verified round 6/7).  FLAGS bit0: +accbuf; bit1: gelu((v+bias)/4)
// ---------------------------------------------------------------------------
template <int FLAGS>
__global__ __launch_bounds__(256, 6) void k_gemm64f(
    const float* __restrict__ Af,
    const ushort_t* __restrict__ Bhi, const ushort_t* __restrict__ Blo,
    int K, int ldb, int nrows,
    const float* __restrict__ accbuf, const float* __restrict__ bias,
    float* __restrict__ Cout)
{
    constexpr int KC = 32;
    __shared__ ushort_t sAh[64 * 32], sAl[64 * 32];
    __shared__ ushort_t sBh[64 * 32], sBl[64 * 32];
    const int tid = threadIdx.x;
    const int w = tid >> 6, ln = tid & 63;
    const int l31 = ln & 31, hl = ln >> 5;
    const int rt = w >> 1, ct = w & 1;
    const int rowbase = blockIdx.x * 64;

    floatx16 acc;
    #pragma unroll
    for (int r = 0; r < 16; ++r) acc[r] = 0.f;

    for (int kc = 0; kc < K; kc += KC) {
        __syncthreads();
        {   // stage A (fp32 -> split) + B (direct-to-LDS), 64 rows each
            int r = tid >> 2, cg = tid & 3;
            int sg = (r ^ (r >> 2)) & 3;
            int row = rowbase + r;
            int sw = r * 32 + ((cg ^ sg) << 3);
            if (row < nrows) {
                size_t ga = (size_t)row * K + kc + cg * 8;
                floatx4 v0 = *(const floatx4*)(Af + ga);
                floatx4 v1 = *(const floatx4*)(Af + ga + 4);
                float vf[8] = {v0.x, v0.y, v0.z, v0.w, v1.x, v1.y, v1.z, v1.w};
                unsigned hu[8], lu[8];
                #pragma unroll
                for (int q = 0; q < 8; ++q) {
                    ushort_t hh = f2bf(vf[q]);
                    hu[q] = hh;
                    lu[q] = f2bf(vf[q] - bf2f(hh));
                }
                uint4 H = make_uint4(hu[0] | (hu[1] << 16), hu[2] | (hu[3] << 16),
                                     hu[4] | (hu[5] << 16), hu[6] | (hu[7] << 16));
                uint4 L = make_uint4(lu[0] | (lu[1] << 16), lu[2] | (lu[3] << 16),
                                     lu[4] | (lu[5] << 16), lu[6] | (lu[7] << 16));
                *(uint4*)&sAh[sw] = H;
                *(uint4*)&sAl[sw] = L;
            } else {
                *(uint4*)&sAh[sw] = make_uint4(0, 0, 0, 0);
                *(uint4*)&sAl[sw] = make_uint4(0, 0, 0, 0);
            }
            int so = r * 32 + (cg << 3);
            size_t gb = (size_t)r * ldb + kc + ((cg ^ sg) << 3);
            gl_lds16(Bhi + gb, &sBh[so]);
            gl_lds16(Blo + gb, &sBl[so]);
        }
        __syncthreads();
        const int arow = (rt << 5) + l31;
        const int brow = (ct << 5) + l31;
        const int sga = (arow ^ (arow >> 2)) & 3;
        const int sgb = (l31 ^ (l31 >> 2)) & 3;
        #pragma unroll
        for (int s = 0; s < 2; ++s) {
            const int c0 = (s << 1) | hl;
            const int ka = (c0 ^ sga) << 3;
            const int kb = (c0 ^ sgb) << 3;
            bf16x8 ah = *(const bf16x8*)&sAh[arow * 32 + ka];
            bf16x8 al = *(const bf16x8*)&sAl[arow * 32 + ka];
            bf16x8 bh = *(const bf16x8*)&sBh[brow * 32 + kb];
            bf16x8 bl = *(const bf16x8*)&sBl[brow * 32 + kb];
            acc = __builtin_amdgcn_mfma_f32_32x32x16_bf16(ah, bh, acc, 0, 0, 0);
            acc = __builtin_amdgcn_mfma_f32_32x32x16_bf16(al, bh, acc, 0, 0, 0);
            acc = __builtin_amdgcn_mfma_f32_32x32x16_bf16(ah, bl, acc, 0, 0, 0);
        }
    }
    // epilogue (C/D layout verified round 6/7)
    int col = (ct << 5) + l31;
    float bv = (FLAGS & 2) ? bias[col] : 0.f;
    #pragma unroll
    for (int r = 0; r < 16; ++r) {
        int row = rowbase + (rt << 5) + (r & 3) + ((r >> 2) << 3) + (hl << 2);
        if (row < nrows) {
            size_t idx = (size_t)row * 64 + col;
            float v = acc[r];
            if (FLAGS & 1) v += accbuf[idx];
            if (FLAGS & 2) v = gelu_exact((v + bv) * 0.25f);
            Cout[idx] = v;
        }
    }
}

// ---------------------------------------------------------------------------
// Feature epilogue: x = gelu(LN(y + lin_b)) + l2norm(emb)
// ---------------------------------------------------------------------------
__global__ __launch_bounds__(256) void k_feat_post(
    const float* __restrict__ y, const float* __restrict__ lin_b,
    const float* __restrict__ ln_g, const float* __restrict__ ln_b,
    const float* __restrict__ emb, float* __restrict__ xout)
{
    int n = (blockIdx.x << 2) + (threadIdx.x >> 6);
    int c = threadIdx.x & 63;
    size_t base = (size_t)n * 64 + c;
    float v = y[base] + lin_b[c];
    float mean = wave_sum64(v) * 0.015625f;
    float t = v - mean;
    float var = wave_sum64(t * t) * 0.015625f;
    float vn = t * (1.0f / sqrtf(var + 1e-5f)) * ln_g[c] + ln_b[c];
    float g = gelu_exact(vn);
    float e = emb[base];
    float nrm = sqrtf(wave_sum64(e * e));
    float xv = g + e / fmaxf(nrm, 1e-12f);
    xout[base] = xv;
}

// ---------------------------------------------------------------------------
// Edge-parallel softmax numerator over REAL edges: one lane = one CSR slot.
// p[t][e][h] = exp(leakyrelu(s_all[src][t*8+h] + s_all[dst][t*8+4+h]))
// ---------------------------------------------------------------------------
__global__ __launch_bounds__(256) void k_edgep(
    const float* __restrict__ s_all, const int2* __restrict__ sd,
    float* __restrict__ parr)
{
    int i = blockIdx.x * 256 + threadIdx.x;
    int t = blockIdx.y;
    if (i >= EE) return;
    size_t base = (size_t)t * EE + i;
    int2 e = sd[base];
    const float4 a = *(const float4*)&s_all[(size_t)e.x * 64 + t * 8];
    const float4 b = *(const float4*)&s_all[(size_t)e.y * 64 + t * 8 + 4];
    float l0 = a.x + b.x, l1 = a.y + b.y;
    float l2 = a.z + b.z, l3 = a.w + b.w;
    l0 = l0 > 0.f ? l0 : 0.2f * l0;
    l1 = l1 > 0.f ? l1 : 0.2f * l1;
    l2 = l2 > 0.f ? l2 : 0.2f * l2;
    l3 = l3 > 0.f ? l3 : 0.2f * l3;
    float4 p = make_float4(__expf(l0), __expf(l1), __expf(l2), __expf(l3));
    *(float4*)&parr[base * 4] = p;
}

// ---------------------------------------------------------------------------
// Edge aggregation for ONE TYPE -> fp32 z [N][256]  (102.4 MB, L3-resident).
// Two independent node-streams per wave (nodes id, id+NN/2) for MLP.
// Self-loops inline (verified round 7).  Grid = NN/8 blocks exactly.
// z[n][h*64+d] = (p_self*x[n,d] + sum_e p_e,h*x[src_e,d]) / S[n,h]
// ---------------------------------------------------------------------------
__global__ __launch_bounds__(256) void k_edge2(
    const float* __restrict__ x, const float* __restrict__ s_all,
    const float* __restrict__ parr, const int* __restrict__ row_ptr,
    const int2* __restrict__ sd, float* __restrict__ zf, int t)
{
    int id = (blockIdx.x << 2) + (threadIdx.x >> 6);   // 0..NN/2-1
    int lane = threadIdx.x & 63;
    const int nA = id, nC = id + (NN / 2);
    int eA = row_ptr[t * (NN + 1) + nA], eA1 = row_ptr[t * (NN + 1) + nA + 1];
    int eC = row_ptr[t * (NN + 1) + nC], eC1 = row_ptr[t * (NN + 1) + nC + 1];
    const int*     sp = (const int*)(sd + (size_t)t * EE);   // .x at stride 2
    const floatx4* pp = (const floatx4*)parr + (size_t)t * EE;

    float xnA = x[(size_t)nA * 64 + lane];
    float xnC = x[(size_t)nC * 64 + lane];

    float a0, a1, a2, a3, SA0, SA1, SA2, SA3;
    float c0, c1, c2, c3, SC0, SC1, SC2, SC3;
    {   // self-loop inits (verified round 7): p_self from s_all[n], x[n]
        const float4 sa = *(const float4*)&s_all[(size_t)nA * 64 + t * 8];
        const float4 sb = *(const float4*)&s_all[(size_t)nA * 64 + t * 8 + 4];
        float l0 = sa.x + sb.x, l1 = sa.y + sb.y;
        float l2 = sa.z + sb.z, l3 = sa.w + sb.w;
        l0 = l0 > 0.f ? l0 : 0.2f * l0;  l1 = l1 > 0.f ? l1 : 0.2f * l1;
        l2 = l2 > 0.f ? l2 : 0.2f * l2;  l3 = l3 > 0.f ? l3 : 0.2f * l3;
        SA0 = __expf(l0); SA1 = __expf(l1); SA2 = __expf(l2); SA3 = __expf(l3);
        a0 = SA0 * xnA; a1 = SA1 * xnA; a2 = SA2 * xnA; a3 = SA3 * xnA;
    }
    {
        const float4 sa = *(const float4*)&s_all[(size_t)nC * 64 + t * 8];
        const float4 sb = *(const float4*)&s_all[(size_t)nC * 64 + t * 8 + 4];
        float l0 = sa.x + sb.x, l1 = sa.y + sb.y;
        float l2 = sa.z + sb.z, l3 = sa.w + sb.w;
        l0 = l0 > 0.f ? l0 : 0.2f * l0;  l1 = l1 > 0.f ? l1 : 0.2f * l1;
        l2 = l2 > 0.f ? l2 : 0.2f * l2;  l3 = l3 > 0.f ? l3 : 0.2f * l3;
        SC0 = __expf(l0); SC1 = __expf(l1); SC2 = __expf(l2); SC3 = __expf(l3);
        c0 = SC0 * xnC; c1 = SC1 * xnC; c2 = SC2 * xnC; c3 = SC3 * xnC;
    }
    int m = (eA1 - eA < eC1 - eC) ? (eA1 - eA) : (eC1 - eC);
    #pragma unroll 2
    for (int q = 0; q < m; ++q) {
        int sA = sp[2 * (eA + q)];                        // wave-uniform
        int sC = sp[2 * (eC + q)];
        floatx4 pa = pp[eA + q];                          // wave-uniform 16B
        floatx4 pc = pp[eC + q];
        float xa = x[(size_t)sA * 64 + lane];             // coalesced 256B
        float xc = x[(size_t)sC * 64 + lane];
        SA0 += pa.x; SA1 += pa.y; SA2 += pa.z; SA3 += pa.w;
        SC0 += pc.x; SC1 += pc.y; SC2 += pc.z; SC3 += pc.w;
        a0 = fmaf(pa.x, xa, a0); a1 = fmaf(pa.y, xa, a1);
        a2 = fmaf(pa.z, xa, a2); a3 = fmaf(pa.w, xa, a3);
        c0 = fmaf(pc.x, xc, c0); c1 = fmaf(pc.y, xc, c1);
        c2 = fmaf(pc.z, xc, c2); c3 = fmaf(pc.w, xc, c3);
    }
    eA += m; eC += m;
    for (; eA < eA1; ++eA) {
        int s = sp[2 * eA]; floatx4 p = pp[eA];
        float xv = x[(size_t)s * 64 + lane];
        SA0 += p.x; SA1 += p.y; SA2 += p.z; SA3 += p.w;
        a0 = fmaf(p.x, xv, a0); a1 = fmaf(p.y, xv, a1);
        a2 = fmaf(p.z, xv, a2); a3 = fmaf(p.w, xv, a3);
    }
    for (; eC < eC1; ++eC) {
        int s = sp[2 * eC]; floatx4 p = pp[eC];
        float xv = x[(size_t)s * 64 + lane];
        SC0 += p.x; SC1 += p.y; SC2 += p.z; SC3 += p.w;
        c0 = fmaf(p.x, xv, c0); c1 = fmaf(p.y, xv, c1);
        c2 = fmaf(p.z, xv, c2); c3 = fmaf(p.w, xv, c3);
    }
    {
        size_t zb = (size_t)nA * 256 + lane;
        zf[zb]       = a0 / SA0;  zf[zb + 64]  = a1 / SA1;
        zf[zb + 128] = a2 / SA2;  zf[zb + 192] = a3 / SA3;
    }
    {
        size_t zb = (size_t)nC * 256 + lane;
        zf[zb]       = c0 / SC0;  zf[zb + 64]  = c1 / SC1;
        zf[zb + 128] = c2 / SC2;  zf[zb + 192] = c3 / SC3;
    }
}

// ---------------------------------------------------------------------------
extern "C" void kernel_launch(void* const* d_in, const int* in_sizes, int n_in,
                              void* d_out, int out_size, void* d_ws, size_t ws_size,
                              hipStream_t stream) {
    const float* fm    = (const float*)d_in[0];
    const float* emb   = (const float*)d_in[1];
    const float* lin_w = (const float*)d_in[2];
    const float* lin_b = (const float*)d_in[3];
    const float* ln_g  = (const float*)d_in[4];
    const float* ln_b  = (const float*)d_in[5];
    const float* Wsrc  = (const float*)d_in[6];
    const float* Wdst  = (const float*)d_in[7];
    const float* asrc  = (const float*)d_in[8];
    const float* adst  = (const float*)d_in[9];
    const float* cbias = (const float*)d_in[10];
    const int*   ei    = (const int*)d_in[11];
    float* out = (float*)d_out;
    (void)in_sizes; (void)n_in; (void)out_size; (void)ws_size;

    char* w = (char*)d_ws;
    size_t off = 0;
    auto alloc = [&](size_t bytes) -> void* {
        void* p = w + off;
        off += (bytes + 255) & ~(size_t)255;
        return p;
    };
    ushort_t* wcTh = (ushort_t*)alloc((size_t)LL * 64 * 64 * 2);
    ushort_t* wcTl = (ushort_t*)alloc((size_t)LL * 64 * 64 * 2);
    ushort_t* lwTh = (ushort_t*)alloc((size_t)64 * 256 * 2);
    ushort_t* lwTl = (ushort_t*)alloc((size_t)64 * 256 * 2);
    ushort_t* bpTh = (ushort_t*)alloc((size_t)LL * 64 * 1024 * 2);
    ushort_t* bpTl = (ushort_t*)alloc((size_t)LL * 64 * 1024 * 2);
    float* bsum    = (float*)alloc((size_t)LL * 64 * 4);
    int*   row_ptr = (int*)  alloc((size_t)TT * (NN + 1) * 4);
    int*   cursor  = (int*)  alloc((size_t)TT * NN * 4);
    int2*  sdarr   = (int2*) alloc((size_t)TT * EE * 8);
    float* parr    = (float*)alloc((size_t)TT * EE * 4 * 4);
    int*   csum    = (int*)  alloc((size_t)TT * NCH * 4);
    int*   cbase   = (int*)  alloc((size_t)TT * NCH * 4);
    float* x       = (float*)alloc(N64 * 4);
    float* s_all   = (float*)alloc(N64 * 4);
    float* accB    = (float*)alloc(N64 * 4);
    // fp32 z for ONE type: [N][256]  (102.4 MB, fits L3 with working set)
    float* zf = (float*)alloc((size_t)NN * 256 * 4);

    hipMemsetAsync(cursor, 0, (size_t)TT * NN * 4, stream);
    k_prep<<<512, 256, 0, stream>>>(Wsrc, Wdst, asrc, adst, cbias, lin_w,
                                    wcTh, wcTl, lwTh, lwTl, bpTh, bpTl, bsum);
    k_hist<<<(TT * EE + 255) / 256, 256, 0, stream>>>(ei, cursor);
    k_scan1<<<TT * NCH, 256, 0, stream>>>(cursor, csum);
    k_scan2<<<1, 64, 0, stream>>>(csum, cbase, row_ptr);
    k_scan3<<<TT * NCH, 256, 0, stream>>>(cursor, cbase, row_ptr);
    k_scatter<<<(TT * EE + 255) / 256, 256, 0, stream>>>(ei, cursor, sdarr);

    const int GB  = (NN + 127) / 128;  // 782 blocks (128 rows each)
    const int GB2 = (NN + 63) / 64;    // 1563 blocks (64 rows each)
    // feature transform: GEMM K=256 (fp32 A, split fused into staging)
    k_gemm_f32a<<<GB, 256, 0, stream>>>(fm, lwTh, lwTl, 256, 256, NN, accB);
    k_feat_post<<<NN / 4, 256, 0, stream>>>(accB, lin_b, ln_g, ln_b, emb, x);

    const dim3 gp((EE + 255) / 256, TT);
    for (int l = 0; l < LL; ++l) {
        float* dest = (l == 0) ? x : out;
        // collapsed attention-logit projection: s_all = x @ wcoll_l  [N,64]
        k_gemm_f32a<<<GB, 256, 0, stream>>>(x, wcTh + l * 4096, wcTl + l * 4096,
                                            64, 64, NN, s_all);
        // edge-parallel p = exp(leaky(logit)) over real edges, all 4 types
        k_edgep<<<gp, 256, 0, stream>>>(s_all, sdarr, parr);
        const ushort_t* Bh = bpTh + (size_t)l * 65536;
        const ushort_t* Bl = bpTl + (size_t)l * 65536;
        // per-type pipeline: z [N][256] stays L3-resident between the two
        for (int t = 0; t < TT; ++t) {
            k_edge2<<<NN / 8, 256, 0, stream>>>(x, s_all, parr, row_ptr,
                                                sdarr, zf, t);
            if (t == 0)
                k_gemm64f<0><<<GB2, 256, 0, stream>>>(zf, Bh + t * 256, Bl + t * 256,
                                                      256, 1024, NN,
                                                      nullptr, nullptr, accB);
            else if (t < TT - 1)
                k_gemm64f<1><<<GB2, 256, 0, stream>>>(zf, Bh + t * 256, Bl + t * 256,
                                                      256, 1024, NN,
                                                      accB, nullptr, accB);
            else
                k_gemm64f<3><<<GB2, 256, 0, stream>>>(zf, Bh + t * 256, Bl + t * 256,
                                                      256, 1024, NN,
                                                      accB, bsum + l * 64, dest);
        }
    }
}